// Round 7
// baseline (494.519 us; speedup 1.0000x reference)
//
#include <hip/hip_runtime.h>
#include <hip/hip_bf16.h>

#define BB 4
#define LL 2048
#define CC 1024
#define HH 16
#define DD 64
#define HALFD 32

typedef short bf16x8 __attribute__((ext_vector_type(8)));
typedef short bf16x4 __attribute__((ext_vector_type(4)));
typedef float f32x4 __attribute__((ext_vector_type(4)));

#if defined(__has_builtin)
#if __has_builtin(__builtin_amdgcn_mfma_f32_16x16x16bf16_1k)
#define HAVE_MFMA16 1
#endif
#endif

__device__ __forceinline__ float bf2f(unsigned short u) {
    union { unsigned int i; float f; } x; x.i = ((unsigned int)u) << 16; return x.f;
}
__device__ __forceinline__ unsigned short f2bf(float f) {
    union { float f; unsigned int i; } x; x.f = f;
    return (unsigned short)((x.i + 0x7fffu + ((x.i >> 16) & 1u)) >> 16);
}
__device__ __forceinline__ unsigned int cvtpk_bf16(float lo, float hi) {
    unsigned int r;
    asm("v_cvt_pk_bf16_f32 %0, %1, %2" : "=v"(r) : "v"(lo), "v"(hi));
    return r;
}
__device__ __forceinline__ float exp2v(float x) {
    float r;
    asm("v_exp_f32 %0, %1" : "=v"(r) : "v"(x));
    return r;
}
__device__ __forceinline__ void gload_lds16(const void* g, void* l) {
    __builtin_amdgcn_global_load_lds(
        (const __attribute__((address_space(1))) unsigned int*)g,
        (__attribute__((address_space(3))) unsigned int*)l, 16, 0, 0);
}

// ---------------- prep: fp32 -> bf16 ----------------
__global__ void k_f2bf(const float4* __restrict__ in, ushort4* __restrict__ out, int n4) {
    int i = blockIdx.x * blockDim.x + threadIdx.x;
    if (i < n4) {
        float4 v = in[i];
        ushort4 o;
        o.x = f2bf(v.x); o.y = f2bf(v.y); o.z = f2bf(v.z); o.w = f2bf(v.w);
        out[i] = o;
    }
}

__global__ void k_biascat(const float* __restrict__ qb, const float* __restrict__ vb,
                          float* __restrict__ out) {
    int i = blockIdx.x * blockDim.x + threadIdx.x;
    if (i < 3 * CC) out[i] = (i < CC) ? qb[i] : (i < 2 * CC ? 0.f : vb[i - 2 * CC]);
}

// ---------------- GEMM: C[M,N] = A[M,K] * Bt[N,K]^T + bias[N] ----------------
// 128x128 tile, BK=32, 4 waves, global_load_lds(16B) staging into linear LDS (m97).
template <typename OutT>
__global__ __launch_bounds__(256) void k_gemm_bt(
    const unsigned short* __restrict__ A, const unsigned short* __restrict__ Bt,
    const float* __restrict__ bias, OutT* __restrict__ Cout, int M, int N, int K) {
    __shared__ unsigned short As[128][32];
    __shared__ unsigned short Bs[128][32];
    int nT = N >> 7;
    int tM = (blockIdx.x / nT) << 7;
    int tN = (blockIdx.x % nT) << 7;
    int t = threadIdx.x;
    int lane = t & 63, wid = t >> 6;
    int wr = (wid >> 1) * 64, wc = (wid & 1) * 64;
    int c = lane & 15, g = lane >> 4;

    const unsigned short* gA = A + (size_t)(tM + wid * 32 + (lane >> 2)) * K + (lane & 3) * 8;
    const unsigned short* gB = Bt + (size_t)(tN + wid * 32 + (lane >> 2)) * K + (lane & 3) * 8;
    unsigned short* lA0 = &As[wid * 32][0];
    unsigned short* lA1 = &As[wid * 32 + 16][0];
    unsigned short* lB0 = &Bs[wid * 32][0];
    unsigned short* lB1 = &Bs[wid * 32 + 16][0];
    size_t r16 = (size_t)16 * K;

    f32x4 acc[4][4];
#pragma unroll
    for (int i = 0; i < 4; i++)
#pragma unroll
        for (int j = 0; j < 4; j++) acc[i][j] = (f32x4){0.f, 0.f, 0.f, 0.f};

    for (int k0 = 0; k0 < K; k0 += 32) {
        __syncthreads();
        gload_lds16(gA + k0, lA0);
        gload_lds16(gA + k0 + r16, lA1);
        gload_lds16(gB + k0, lB0);
        gload_lds16(gB + k0 + r16, lB1);
        __syncthreads();
        bf16x8 af[4], bfr[4];
#pragma unroll
        for (int fm = 0; fm < 4; fm++) af[fm] = *(const bf16x8*)&As[wr + fm * 16 + c][g * 8];
#pragma unroll
        for (int fn = 0; fn < 4; fn++) bfr[fn] = *(const bf16x8*)&Bs[wc + fn * 16 + c][g * 8];
#pragma unroll
        for (int fm = 0; fm < 4; fm++)
#pragma unroll
            for (int fn = 0; fn < 4; fn++)
                acc[fm][fn] = __builtin_amdgcn_mfma_f32_16x16x32_bf16(af[fm], bfr[fn],
                                                                      acc[fm][fn], 0, 0, 0);
    }
#pragma unroll
    for (int fm = 0; fm < 4; fm++) {
#pragma unroll
        for (int fn = 0; fn < 4; fn++) {
            int col = tN + wc + fn * 16 + c;
            float bv = bias[col];
#pragma unroll
            for (int r = 0; r < 4; r++) {
                int row = tM + wr + fm * 16 + g * 4 + r;
                float v = acc[fm][fn][r] + bv;
                if constexpr (sizeof(OutT) == 2)
                    Cout[(size_t)row * N + col] = f2bf(v);
                else
                    Cout[(size_t)row * N + col] = v;
            }
        }
    }
}

// ---------------- Q/K: l2norm + scale(+log2e) + RoPE, layout (B,H,L,D) bf16 ----------------
__global__ __launch_bounds__(256) void k_qknorm(
    const unsigned short* __restrict__ qkv, const float* __restrict__ rope,
    const float* __restrict__ smul, unsigned short* __restrict__ Q,
    unsigned short* __restrict__ Ko) {
    int wid = threadIdx.x >> 6, lane = threadIdx.x & 63;
    long rowid = (long)blockIdx.x * 4 + wid;  // (b,l,h), h fastest
    int h = rowid & 15;
    long t2 = rowid >> 4;
    int l = t2 & 2047;
    int b = (int)(t2 >> 11);
    size_t base = ((size_t)(b * LL + l) * 3) * CC + h * 64 + lane;
    float q = bf2f(qkv[base]);
    float k = bf2f(qkv[base + CC]);
    float sq = q * q, sk = k * k;
#pragma unroll
    for (int m = 32; m >= 1; m >>= 1) {
        sq += __shfl_xor(sq, m);
        sk += __shfl_xor(sk, m);
    }
    // fold log2(e) into the q scale: softmax then uses exp2 directly (exact cancellation)
    float sm = expf(fminf(smul[h], 4.6051701859880913680f)) * 1.4426950408889634f;
    q = q / fmaxf(sqrtf(sq), 1e-12f) * sm;
    k = k / fmaxf(sqrtf(sk), 1e-12f);
    int j = lane >> 1;
    float cs = rope[((size_t)(b * 2) * LL + l) * HALFD + j];
    float sn = rope[((size_t)(b * 2 + 1) * LL + l) * HALFD + j];
    float qp = __shfl_xor(q, 1), kp = __shfl_xor(k, 1);
    float qn = (lane & 1) ? (qp * sn + q * cs) : (q * cs - qp * sn);
    float kn = (lane & 1) ? (kp * sn + k * cs) : (k * cs - kp * sn);
    size_t ob = ((size_t)(b * HH + h) * LL + l) * 64 + lane;
    Q[ob] = f2bf(qn);
    Ko[ob] = f2bf(kn);
}

// ---------------- V transpose: (B,L,H,D) slice of qkv -> Vt (B,H,D,L) bf16 ----------------
__global__ __launch_bounds__(256) void k_vtrans(const unsigned short* __restrict__ qkv,
                                               unsigned short* __restrict__ Vt) {
    __shared__ unsigned short tile[64][65];
    int bid = blockIdx.x;
    int lb = bid & 31;  // L/64
    int bh = bid >> 5;
    int h = bh & 15, b = bh >> 4;
    int t = threadIdx.x;
    for (int i = t; i < 4096; i += 256) {
        int row = i >> 6, dd = i & 63;
        tile[row][dd] = qkv[((size_t)(b * LL + lb * 64 + row) * 3 + 2) * CC + h * 64 + dd];
    }
    __syncthreads();
    for (int i = t; i < 4096; i += 256) {
        int dd = i >> 6, l2 = i & 63;
        Vt[((size_t)bh * 64 + dd) * LL + lb * 64 + l2] = tile[l2][dd];
    }
}

// ---------------- causal flash attention: uniform tile-pairs, two phases ----------------
// Each wave owns q-tile pair (i, 127-i), 16 rows each, processed as TWO sequential
// phases. Per-wave k-work = 129*16 for EVERY wave -> 4096 exactly-uniform waves
// (16/CU = 4/SIMD, flat occupancy, no imbalance tail). Phase body = the proven
// round-2/5 code: KVBLK=32, swapped-QK^T (S^T col=q=lane&15, row k=4g+reg ->
// P lane-local), defer-max, exp2-domain, cvtpk, register-direct PV.
__global__ __launch_bounds__(256) void k_attn(
    const unsigned short* __restrict__ Q, const unsigned short* __restrict__ K,
    const unsigned short* __restrict__ Vt, unsigned short* __restrict__ Out) {
    int lane = threadIdx.x & 63, wid = threadIdx.x >> 6;
    int c = lane & 15, g = lane >> 4;
    int bid = blockIdx.x;
    int xcd = bid & 7;
    int idx = bid >> 3;            // 0..127
    int hgrp = idx >> 4;           // 0..7
    int pblk = idx & 15;           // 0..15
    int bh = hgrp * 8 + xcd;       // 8 heads per XCD cluster -> K/V fits one L2
    int pi = pblk * 4 + wid;       // 0..63: this wave's tile pair (pi, 127-pi)
    const unsigned short* Qh = Q + (size_t)bh * LL * 64;
    const unsigned short* Kh = K + (size_t)bh * LL * 64;
    const unsigned short* Vh = Vt + (size_t)bh * 64 * LL;
    int b = bh >> 4, h = bh & 15;

#ifndef HAVE_MFMA16
    int srcA = 32 * (g & 1) + c;
    int srcB = srcA + 16;
#endif

    for (int ph = 0; ph < 2; ++ph) {
        int q0 = ph ? (2032 - 16 * pi) : (16 * pi);
        int qrow = q0 + c;
        bf16x8 qf0 = *(const bf16x8*)&Qh[(size_t)(q0 + c) * 64 + g * 8];
        bf16x8 qf1 = *(const bf16x8*)&Qh[(size_t)(q0 + c) * 64 + 32 + g * 8];

        f32x4 acc[4];
#pragma unroll
        for (int dt = 0; dt < 4; dt++) acc[dt] = (f32x4){0.f, 0.f, 0.f, 0.f};
        float m_ = -1e30f, l_ = 0.f;

        for (int kt = 0; kt < q0 + 16; kt += 32) {
            bf16x8 kf[2][2];
#pragma unroll
            for (int kt2 = 0; kt2 < 2; kt2++)
#pragma unroll
                for (int ch = 0; ch < 2; ch++)
                    kf[kt2][ch] = *(const bf16x8*)&Kh[(size_t)(kt + kt2 * 16 + c) * 64 +
                                                      ch * 32 + g * 8];
#ifdef HAVE_MFMA16
            bf16x4 vf[4][2];  // [dt][kt2]: row=d=dt*16+c, kk(k)=4g+e
#pragma unroll
            for (int dt = 0; dt < 4; dt++)
#pragma unroll
                for (int kt2 = 0; kt2 < 2; kt2++)
                    vf[dt][kt2] = *(const bf16x4*)&Vh[(size_t)(dt * 16 + c) * LL + kt +
                                                      kt2 * 16 + 4 * g];
#else
            bf16x8 vf8[4];
#pragma unroll
            for (int dt = 0; dt < 4; dt++)
                vf8[dt] = *(const bf16x8*)&Vh[(size_t)(dt * 16 + c) * LL + kt + 8 * g];
#endif
            f32x4 sv[2];
            __builtin_amdgcn_s_setprio(1);
#pragma unroll
            for (int kt2 = 0; kt2 < 2; kt2++) {
                sv[kt2] = (f32x4){0.f, 0.f, 0.f, 0.f};
                sv[kt2] = __builtin_amdgcn_mfma_f32_16x16x32_bf16(kf[kt2][0], qf0,
                                                                  sv[kt2], 0, 0, 0);
                sv[kt2] = __builtin_amdgcn_mfma_f32_16x16x32_bf16(kf[kt2][1], qf1,
                                                                  sv[kt2], 0, 0, 0);
            }
            __builtin_amdgcn_s_setprio(0);
            if (kt + 31 > q0) {
#pragma unroll
                for (int kt2 = 0; kt2 < 2; kt2++) {
                    if (kt + kt2 * 16 + 15 > q0) {
#pragma unroll
                        for (int r = 0; r < 4; r++)
                            if (kt + kt2 * 16 + 4 * g + r > qrow) sv[kt2][r] = -1e9f;
                    }
                }
            }
            float tm = fmaxf(fmaxf(fmaxf(sv[0][0], sv[0][1]), fmaxf(sv[0][2], sv[0][3])),
                             fmaxf(fmaxf(sv[1][0], sv[1][1]), fmaxf(sv[1][2], sv[1][3])));
            tm = fmaxf(tm, __shfl_xor(tm, 16));
            tm = fmaxf(tm, __shfl_xor(tm, 32));
            // defer-max: logits bounded (|s*log2e| <= ~5.8) -> rescale fires ~once
            if (__any(tm > m_ + 12.0f)) {
                float mn = fmaxf(m_, tm);
                float scl = exp2v(m_ - mn);
                m_ = mn;
                l_ *= scl;
#pragma unroll
                for (int dt = 0; dt < 4; dt++) {
                    acc[dt][0] *= scl; acc[dt][1] *= scl;
                    acc[dt][2] *= scl; acc[dt][3] *= scl;
                }
            }
            float p0[4], p1[4];
            float rs = 0.f;
#pragma unroll
            for (int r = 0; r < 4; r++) {
                p0[r] = exp2v(sv[0][r] - m_);
                p1[r] = exp2v(sv[1][r] - m_);
                rs += p0[r] + p1[r];
            }
            rs += __shfl_xor(rs, 16);
            rs += __shfl_xor(rs, 32);
            l_ += rs;
#ifdef HAVE_MFMA16
            bf16x4 pb0, pb1;
            {
                union { unsigned int w[2]; bf16x4 v; } u0, u1;
                u0.w[0] = cvtpk_bf16(p0[0], p0[1]);
                u0.w[1] = cvtpk_bf16(p0[2], p0[3]);
                u1.w[0] = cvtpk_bf16(p1[0], p1[1]);
                u1.w[1] = cvtpk_bf16(p1[2], p1[3]);
                pb0 = u0.v; pb1 = u1.v;
            }
            __builtin_amdgcn_s_setprio(1);
#pragma unroll
            for (int dt = 0; dt < 4; dt++) {
                acc[dt] = __builtin_amdgcn_mfma_f32_16x16x16bf16_1k(vf[dt][0], pb0,
                                                                    acc[dt], 0, 0, 0);
                acc[dt] = __builtin_amdgcn_mfma_f32_16x16x16bf16_1k(vf[dt][1], pb1,
                                                                    acc[dt], 0, 0, 0);
            }
            __builtin_amdgcn_s_setprio(0);
#else
            // build K=32 B-frag (kk=8g+e) via 8 shuffles (proven round-2 mapping)
            unsigned int A0 = cvtpk_bf16(p0[0], p0[1]);
            unsigned int A1 = cvtpk_bf16(p0[2], p0[3]);
            unsigned int B0 = cvtpk_bf16(p1[0], p1[1]);
            unsigned int B1 = cvtpk_bf16(p1[2], p1[3]);
            int t0a = __shfl((int)A0, srcA), t0b = __shfl((int)B0, srcA);
            int t1a = __shfl((int)A1, srcA), t1b = __shfl((int)B1, srcA);
            int t2a = __shfl((int)A0, srcB), t2b = __shfl((int)B0, srcB);
            int t3a = __shfl((int)A1, srcB), t3b = __shfl((int)B1, srcB);
            union { int w[4]; bf16x8 v; } u;
            bool hi = (g & 2) != 0;
            u.w[0] = hi ? t0b : t0a;
            u.w[1] = hi ? t1b : t1a;
            u.w[2] = hi ? t2b : t2a;
            u.w[3] = hi ? t3b : t3a;
#pragma unroll
            for (int dt = 0; dt < 4; dt++)
                acc[dt] = __builtin_amdgcn_mfma_f32_16x16x32_bf16(vf8[dt], u.v,
                                                                  acc[dt], 0, 0, 0);
#endif
        }
        // epilogue: Out (B,L,C) bf16; lane writes d = dt*16 + 4g + r, q = q0+c
        float inv = 1.f / l_;
        size_t ob = ((size_t)b * LL + (q0 + c)) * CC + h * 64;
#pragma unroll
        for (int dt = 0; dt < 4; dt++) {
            union { unsigned int w[2]; ushort4 v; } o;
            o.w[0] = cvtpk_bf16(acc[dt][0] * inv, acc[dt][1] * inv);
            o.w[1] = cvtpk_bf16(acc[dt][2] * inv, acc[dt][3] * inv);
            *(ushort4*)&Out[ob + dt * 16 + 4 * g] = o.v;
        }
    }
}

extern "C" void kernel_launch(void* const* d_in, const int* in_sizes, int n_in,
                              void* d_out, int out_size, void* d_ws, size_t ws_size,
                              hipStream_t stream) {
    const float* x = (const float*)d_in[0];
    const float* rope = (const float*)d_in[2];
    const float* w1 = (const float*)d_in[3];
    const float* qb = (const float*)d_in[4];
    const float* vb = (const float*)d_in[5];
    const float* w2 = (const float*)d_in[6];
    const float* pb = (const float*)d_in[7];
    const float* smul = (const float*)d_in[8];
    float* out = (float*)d_out;

    char* ws = (char*)d_ws;
    unsigned short* xb = (unsigned short*)(ws + 0);                 // 16777216 B
    unsigned short* w1b = (unsigned short*)(ws + 16777216);         // 6291456
    unsigned short* w2b = (unsigned short*)(ws + 23068672);         // 2097152
    float* biascat = (float*)(ws + 25165824);                       // 12288
    unsigned short* qkvb = (unsigned short*)(ws + 25178112);        // 50331648
    unsigned short* Qb = (unsigned short*)(ws + 75509760);          // 16777216
    unsigned short* Kb = (unsigned short*)(ws + 92286976);          // 16777216
    unsigned short* Vtb = (unsigned short*)(ws + 109064192);        // 16777216
    unsigned short* attb = (unsigned short*)(ws + 125841408);       // 16777216
    if (ws_size < 142618624) return;

    int n4;
    n4 = BB * LL * CC / 4;
    k_f2bf<<<(n4 + 255) / 256, 256, 0, stream>>>((const float4*)x, (ushort4*)xb, n4);
    n4 = 3 * CC * CC / 4;
    k_f2bf<<<(n4 + 255) / 256, 256, 0, stream>>>((const float4*)w1, (ushort4*)w1b, n4);
    n4 = CC * CC / 4;
    k_f2bf<<<(n4 + 255) / 256, 256, 0, stream>>>((const float4*)w2, (ushort4*)w2b, n4);
    k_biascat<<<12, 256, 0, stream>>>(qb, vb, biascat);

    k_gemm_bt<unsigned short><<<(8192 / 128) * (3072 / 128), 256, 0, stream>>>(
        xb, w1b, biascat, qkvb, BB * LL, 3 * CC, CC);

    k_qknorm<<<BB * LL * HH / 4, 256, 0, stream>>>(qkvb, rope, smul, Qb, Kb);
    k_vtrans<<<BB * HH * (LL / 64), 256, 0, stream>>>(qkvb, Vtb);
    k_attn<<<1024, 256, 0, stream>>>(Qb, Kb, Vtb, attb);

    k_gemm_bt<float><<<(8192 / 128) * (1024 / 128), 256, 0, stream>>>(
        attb, w2b, pb, out, BB * LL, CC, CC);
}

// Round 9
// 333.759 us; speedup vs baseline: 1.4817x; 1.4817x over previous
//
#include <hip/hip_runtime.h>
#include <hip/hip_bf16.h>

#define BB 4
#define LL 2048
#define CC 1024
#define HH 16
#define DD 64
#define HALFD 32

typedef short bf16x8 __attribute__((ext_vector_type(8)));
typedef short bf16x4 __attribute__((ext_vector_type(4)));
typedef float f32x4 __attribute__((ext_vector_type(4)));

#if defined(__has_builtin)
#if __has_builtin(__builtin_amdgcn_mfma_f32_16x16x16bf16_1k)
#define HAVE_MFMA16 1
#endif
#endif

__device__ __forceinline__ float bf2f(unsigned short u) {
    union { unsigned int i; float f; } x; x.i = ((unsigned int)u) << 16; return x.f;
}
__device__ __forceinline__ unsigned short f2bf(float f) {
    union { float f; unsigned int i; } x; x.f = f;
    return (unsigned short)((x.i + 0x7fffu + ((x.i >> 16) & 1u)) >> 16);
}
__device__ __forceinline__ unsigned int cvtpk_bf16(float lo, float hi) {
    unsigned int r;
    asm("v_cvt_pk_bf16_f32 %0, %1, %2" : "=v"(r) : "v"(lo), "v"(hi));
    return r;
}
__device__ __forceinline__ float exp2v(float x) {
    float r;
    asm("v_exp_f32 %0, %1" : "=v"(r) : "v"(x));
    return r;
}
__device__ __forceinline__ void gload_lds16(const void* g, void* l) {
    __builtin_amdgcn_global_load_lds(
        (const __attribute__((address_space(1))) unsigned int*)g,
        (__attribute__((address_space(3))) unsigned int*)l, 16, 0, 0);
}

// ---------------- prep: fp32 -> bf16 ----------------
__global__ void k_f2bf(const float4* __restrict__ in, ushort4* __restrict__ out, int n4) {
    int i = blockIdx.x * blockDim.x + threadIdx.x;
    if (i < n4) {
        float4 v = in[i];
        ushort4 o;
        o.x = f2bf(v.x); o.y = f2bf(v.y); o.z = f2bf(v.z); o.w = f2bf(v.w);
        out[i] = o;
    }
}

__global__ void k_biascat(const float* __restrict__ qb, const float* __restrict__ vb,
                          float* __restrict__ out) {
    int i = blockIdx.x * blockDim.x + threadIdx.x;
    if (i < 3 * CC) out[i] = (i < CC) ? qb[i] : (i < 2 * CC ? 0.f : vb[i - 2 * CC]);
}

// ---------------- GEMM: C[M,N] = A[M,K] * Bt[N,K]^T + bias[N] ----------------
// 128x128 tile, BK=32, 4 waves, global_load_lds(16B) staging into linear LDS (m97).
template <typename OutT>
__global__ __launch_bounds__(256) void k_gemm_bt(
    const unsigned short* __restrict__ A, const unsigned short* __restrict__ Bt,
    const float* __restrict__ bias, OutT* __restrict__ Cout, int M, int N, int K) {
    __shared__ unsigned short As[128][32];
    __shared__ unsigned short Bs[128][32];
    int nT = N >> 7;
    int tM = (blockIdx.x / nT) << 7;
    int tN = (blockIdx.x % nT) << 7;
    int t = threadIdx.x;
    int lane = t & 63, wid = t >> 6;
    int wr = (wid >> 1) * 64, wc = (wid & 1) * 64;
    int c = lane & 15, g = lane >> 4;

    const unsigned short* gA = A + (size_t)(tM + wid * 32 + (lane >> 2)) * K + (lane & 3) * 8;
    const unsigned short* gB = Bt + (size_t)(tN + wid * 32 + (lane >> 2)) * K + (lane & 3) * 8;
    unsigned short* lA0 = &As[wid * 32][0];
    unsigned short* lA1 = &As[wid * 32 + 16][0];
    unsigned short* lB0 = &Bs[wid * 32][0];
    unsigned short* lB1 = &Bs[wid * 32 + 16][0];
    size_t r16 = (size_t)16 * K;

    f32x4 acc[4][4];
#pragma unroll
    for (int i = 0; i < 4; i++)
#pragma unroll
        for (int j = 0; j < 4; j++) acc[i][j] = (f32x4){0.f, 0.f, 0.f, 0.f};

    for (int k0 = 0; k0 < K; k0 += 32) {
        __syncthreads();
        gload_lds16(gA + k0, lA0);
        gload_lds16(gA + k0 + r16, lA1);
        gload_lds16(gB + k0, lB0);
        gload_lds16(gB + k0 + r16, lB1);
        __syncthreads();
        bf16x8 af[4], bfr[4];
#pragma unroll
        for (int fm = 0; fm < 4; fm++) af[fm] = *(const bf16x8*)&As[wr + fm * 16 + c][g * 8];
#pragma unroll
        for (int fn = 0; fn < 4; fn++) bfr[fn] = *(const bf16x8*)&Bs[wc + fn * 16 + c][g * 8];
#pragma unroll
        for (int fm = 0; fm < 4; fm++)
#pragma unroll
            for (int fn = 0; fn < 4; fn++)
                acc[fm][fn] = __builtin_amdgcn_mfma_f32_16x16x32_bf16(af[fm], bfr[fn],
                                                                      acc[fm][fn], 0, 0, 0);
    }
#pragma unroll
    for (int fm = 0; fm < 4; fm++) {
#pragma unroll
        for (int fn = 0; fn < 4; fn++) {
            int col = tN + wc + fn * 16 + c;
            float bv = bias[col];
#pragma unroll
            for (int r = 0; r < 4; r++) {
                int row = tM + wr + fm * 16 + g * 4 + r;
                float v = acc[fm][fn][r] + bv;
                if constexpr (sizeof(OutT) == 2)
                    Cout[(size_t)row * N + col] = f2bf(v);
                else
                    Cout[(size_t)row * N + col] = v;
            }
        }
    }
}

// ---------------- Q/K: l2norm + scale(+log2e) + RoPE, layout (B,H,L,D) bf16 ----------------
__global__ __launch_bounds__(256) void k_qknorm(
    const unsigned short* __restrict__ qkv, const float* __restrict__ rope,
    const float* __restrict__ smul, unsigned short* __restrict__ Q,
    unsigned short* __restrict__ Ko) {
    int wid = threadIdx.x >> 6, lane = threadIdx.x & 63;
    long rowid = (long)blockIdx.x * 4 + wid;  // (b,l,h), h fastest
    int h = rowid & 15;
    long t2 = rowid >> 4;
    int l = t2 & 2047;
    int b = (int)(t2 >> 11);
    size_t base = ((size_t)(b * LL + l) * 3) * CC + h * 64 + lane;
    float q = bf2f(qkv[base]);
    float k = bf2f(qkv[base + CC]);
    float sq = q * q, sk = k * k;
#pragma unroll
    for (int m = 32; m >= 1; m >>= 1) {
        sq += __shfl_xor(sq, m);
        sk += __shfl_xor(sk, m);
    }
    // fold log2(e) into the q scale: softmax then uses exp2 directly (exact cancellation)
    float sm = expf(fminf(smul[h], 4.6051701859880913680f)) * 1.4426950408889634f;
    q = q / fmaxf(sqrtf(sq), 1e-12f) * sm;
    k = k / fmaxf(sqrtf(sk), 1e-12f);
    int j = lane >> 1;
    float cs = rope[((size_t)(b * 2) * LL + l) * HALFD + j];
    float sn = rope[((size_t)(b * 2 + 1) * LL + l) * HALFD + j];
    float qp = __shfl_xor(q, 1), kp = __shfl_xor(k, 1);
    float qn = (lane & 1) ? (qp * sn + q * cs) : (q * cs - qp * sn);
    float kn = (lane & 1) ? (kp * sn + k * cs) : (k * cs - kp * sn);
    size_t ob = ((size_t)(b * HH + h) * LL + l) * 64 + lane;
    Q[ob] = f2bf(qn);
    Ko[ob] = f2bf(kn);
}

// ---------------- V transpose: (B,L,H,D) slice of qkv -> Vt (B,H,D,L) bf16 ----------------
__global__ __launch_bounds__(256) void k_vtrans(const unsigned short* __restrict__ qkv,
                                               unsigned short* __restrict__ Vt) {
    __shared__ unsigned short tile[64][65];
    int bid = blockIdx.x;
    int lb = bid & 31;  // L/64
    int bh = bid >> 5;
    int h = bh & 15, b = bh >> 4;
    int t = threadIdx.x;
    for (int i = t; i < 4096; i += 256) {
        int row = i >> 6, dd = i & 63;
        tile[row][dd] = qkv[((size_t)(b * LL + lb * 64 + row) * 3 + 2) * CC + h * 64 + dd];
    }
    __syncthreads();
    for (int i = t; i < 4096; i += 256) {
        int dd = i >> 6, l2 = i & 63;
        Vt[((size_t)bh * 64 + dd) * LL + lb * 64 + l2] = tile[l2][dd];
    }
}

// ---------------- causal flash attention: balanced strip-pair blocks, two phases ----------------
// 512 blocks (64 heads x 8 pairs). Block runs the PROVEN r5 body twice: phase 0 on
// strip j, phase 1 on strip 15-j (128 rows each; wave = 32 rows; k-loop to own
// diagonal). Per-block k-work = (j + 15-j)*const + c0 -> IDENTICAL for all blocks;
// 512 blocks = exactly 2/CU co-resident, flat occupancy, zero tail.
// Body: swapped-QK^T (S^T col=q=lane&15, row k=4g+reg -> P lane-local), KVBLK=64,
// defer-max (log2 domain), exp2 softmax, cvtpk, register-direct PV.
__global__ __launch_bounds__(256) void k_attn(
    const unsigned short* __restrict__ Q, const unsigned short* __restrict__ K,
    const unsigned short* __restrict__ Vt, unsigned short* __restrict__ Out) {
    int lane = threadIdx.x & 63, wid = threadIdx.x >> 6;
    int c = lane & 15, g = lane >> 4;
    int bid = blockIdx.x;
    int xcd = bid & 7;
    int hgrp = (bid >> 3) & 7;
    int jp = bid >> 6;             // 0..7: pair index
    int bh = hgrp * 8 + xcd;       // 8 heads per XCD cluster -> K/V fits one L2
    const unsigned short* Qh = Q + (size_t)bh * LL * 64;
    const unsigned short* Kh = K + (size_t)bh * LL * 64;
    const unsigned short* Vh = Vt + (size_t)bh * 64 * LL;
    int b = bh >> 4, h = bh & 15;

#ifndef HAVE_MFMA16
    int srcA = 32 * (g & 1) + c;
    int srcB = srcA + 16;
#endif

#pragma unroll 1
    for (int ph = 0; ph < 2; ++ph) {
        int strip = ph ? (15 - jp) : jp;
        int qb = strip * 128 + wid * 32;

        bf16x8 qf[2][2];
#pragma unroll
        for (int qt = 0; qt < 2; qt++)
#pragma unroll
            for (int ch = 0; ch < 2; ch++)
                qf[qt][ch] =
                    *(const bf16x8*)&Qh[(size_t)(qb + qt * 16 + c) * 64 + ch * 32 + g * 8];

        f32x4 acc[2][4];  // [qt][dtile] of out^T: col=q=c, row=d=4g+r
#pragma unroll
        for (int qt = 0; qt < 2; qt++)
#pragma unroll
            for (int dt = 0; dt < 4; dt++) acc[qt][dt] = (f32x4){0.f, 0.f, 0.f, 0.f};
        float m_[2] = {-1e30f, -1e30f}, l_[2] = {0.f, 0.f};

#pragma unroll 1
        for (int kt = 0; kt < qb + 32; kt += 64) {
            bf16x8 kf[4][2];
#pragma unroll
            for (int kt2 = 0; kt2 < 4; kt2++)
#pragma unroll
                for (int ch = 0; ch < 2; ch++)
                    kf[kt2][ch] =
                        *(const bf16x8*)&Kh[(size_t)(kt + kt2 * 16 + c) * 64 + ch * 32 + g * 8];
#ifdef HAVE_MFMA16
            bf16x4 vf[4][4];  // [dt][kt2]: row=d=dt*16+c, kk(k)=4g+e
#pragma unroll
            for (int dt = 0; dt < 4; dt++)
#pragma unroll
                for (int kt2 = 0; kt2 < 4; kt2++)
                    vf[dt][kt2] =
                        *(const bf16x4*)&Vh[(size_t)(dt * 16 + c) * LL + kt + kt2 * 16 + 4 * g];
#else
            bf16x8 vf8[4][2];
#pragma unroll
            for (int dt = 0; dt < 4; dt++)
#pragma unroll
                for (int hf = 0; hf < 2; hf++)
                    vf8[dt][hf] =
                        *(const bf16x8*)&Vh[(size_t)(dt * 16 + c) * LL + kt + hf * 32 + 8 * g];
#endif
#pragma unroll
            for (int qt = 0; qt < 2; qt++) {
                int qtb = qb + qt * 16;
                if (kt > qtb + 15) continue;  // this tile finished (wave-uniform)
                int qrow = qtb + c;
                f32x4 sv[4];
                __builtin_amdgcn_s_setprio(1);
#pragma unroll
                for (int kt2 = 0; kt2 < 4; kt2++) {
                    sv[kt2] = (f32x4){0.f, 0.f, 0.f, 0.f};
                    sv[kt2] = __builtin_amdgcn_mfma_f32_16x16x32_bf16(kf[kt2][0], qf[qt][0],
                                                                      sv[kt2], 0, 0, 0);
                    sv[kt2] = __builtin_amdgcn_mfma_f32_16x16x32_bf16(kf[kt2][1], qf[qt][1],
                                                                      sv[kt2], 0, 0, 0);
                }
                __builtin_amdgcn_s_setprio(0);
                if (kt + 63 > qtb) {
#pragma unroll
                    for (int kt2 = 0; kt2 < 4; kt2++) {
                        if (kt + kt2 * 16 + 15 > qtb) {
#pragma unroll
                            for (int r = 0; r < 4; r++)
                                if (kt + kt2 * 16 + 4 * g + r > qrow) sv[kt2][r] = -1e9f;
                        }
                    }
                }
                float tm = fmaxf(fmaxf(fmaxf(sv[0][0], sv[0][1]), fmaxf(sv[0][2], sv[0][3])),
                                 fmaxf(fmaxf(sv[1][0], sv[1][1]), fmaxf(sv[1][2], sv[1][3])));
                float tm2 = fmaxf(fmaxf(fmaxf(sv[2][0], sv[2][1]), fmaxf(sv[2][2], sv[2][3])),
                                  fmaxf(fmaxf(sv[3][0], sv[3][1]), fmaxf(sv[3][2], sv[3][3])));
                tm = fmaxf(tm, tm2);
                tm = fmaxf(tm, __shfl_xor(tm, 16));
                tm = fmaxf(tm, __shfl_xor(tm, 32));
                // defer-max: logits bounded (|s*log2e| <= ~5.8) -> rescale fires ~once
                if (__any(tm > m_[qt] + 12.0f)) {
                    float mn = fmaxf(m_[qt], tm);
                    float scl = exp2v(m_[qt] - mn);
                    m_[qt] = mn;
                    l_[qt] *= scl;
#pragma unroll
                    for (int dt = 0; dt < 4; dt++) {
                        acc[qt][dt][0] *= scl; acc[qt][dt][1] *= scl;
                        acc[qt][dt][2] *= scl; acc[qt][dt][3] *= scl;
                    }
                }
                float p[4][4];
                float rs = 0.f;
#pragma unroll
                for (int kt2 = 0; kt2 < 4; kt2++)
#pragma unroll
                    for (int r = 0; r < 4; r++) {
                        p[kt2][r] = exp2v(sv[kt2][r] - m_[qt]);
                        rs += p[kt2][r];
                    }
                rs += __shfl_xor(rs, 16);
                rs += __shfl_xor(rs, 32);
                l_[qt] += rs;
#ifdef HAVE_MFMA16
                bf16x4 pbv[4];
#pragma unroll
                for (int kt2 = 0; kt2 < 4; kt2++) {
                    union { unsigned int w[2]; bf16x4 v; } pu;
                    pu.w[0] = cvtpk_bf16(p[kt2][0], p[kt2][1]);
                    pu.w[1] = cvtpk_bf16(p[kt2][2], p[kt2][3]);
                    pbv[kt2] = pu.v;
                }
                __builtin_amdgcn_s_setprio(1);
#pragma unroll
                for (int dt = 0; dt < 4; dt++)
#pragma unroll
                    for (int kt2 = 0; kt2 < 4; kt2++)
                        acc[qt][dt] = __builtin_amdgcn_mfma_f32_16x16x16bf16_1k(
                            vf[dt][kt2], pbv[kt2], acc[qt][dt], 0, 0, 0);
                __builtin_amdgcn_s_setprio(0);
#else
#pragma unroll
                for (int hf = 0; hf < 2; hf++) {
                    unsigned int A0 = cvtpk_bf16(p[2 * hf][0], p[2 * hf][1]);
                    unsigned int A1 = cvtpk_bf16(p[2 * hf][2], p[2 * hf][3]);
                    unsigned int B0 = cvtpk_bf16(p[2 * hf + 1][0], p[2 * hf + 1][1]);
                    unsigned int B1 = cvtpk_bf16(p[2 * hf + 1][2], p[2 * hf + 1][3]);
                    int t0a = __shfl((int)A0, srcA), t0b = __shfl((int)B0, srcA);
                    int t1a = __shfl((int)A1, srcA), t1b = __shfl((int)B1, srcA);
                    int t2a = __shfl((int)A0, srcB), t2b = __shfl((int)B0, srcB);
                    int t3a = __shfl((int)A1, srcB), t3b = __shfl((int)B1, srcB);
                    union { int w[4]; bf16x8 v; } u;
                    bool hi = (g & 2) != 0;
                    u.w[0] = hi ? t0b : t0a;
                    u.w[1] = hi ? t1b : t1a;
                    u.w[2] = hi ? t2b : t2a;
                    u.w[3] = hi ? t3b : t3a;
#pragma unroll
                    for (int dt = 0; dt < 4; dt++)
                        acc[qt][dt] = __builtin_amdgcn_mfma_f32_16x16x32_bf16(
                            vf8[dt][hf], u.v, acc[qt][dt], 0, 0, 0);
                }
#endif
            }
        }
        // epilogue: Out (B,L,C) bf16; lane writes d = dt*16 + 4g + r, q = qb+qt*16+c
#pragma unroll
        for (int qt = 0; qt < 2; qt++) {
            float inv = 1.f / l_[qt];
            int qg = qb + qt * 16 + c;
            size_t ob = ((size_t)b * LL + qg) * CC + h * 64;
#pragma unroll
            for (int dt = 0; dt < 4; dt++) {
                union { unsigned int w[2]; ushort4 v; } o;
                o.w[0] = cvtpk_bf16(acc[qt][dt][0] * inv, acc[qt][dt][1] * inv);
                o.w[1] = cvtpk_bf16(acc[qt][dt][2] * inv, acc[qt][dt][3] * inv);
                *(ushort4*)&Out[ob + dt * 16 + 4 * g] = o.v;
            }
        }
    }
}

extern "C" void kernel_launch(void* const* d_in, const int* in_sizes, int n_in,
                              void* d_out, int out_size, void* d_ws, size_t ws_size,
                              hipStream_t stream) {
    const float* x = (const float*)d_in[0];
    const float* rope = (const float*)d_in[2];
    const float* w1 = (const float*)d_in[3];
    const float* qb = (const float*)d_in[4];
    const float* vb = (const float*)d_in[5];
    const float* w2 = (const float*)d_in[6];
    const float* pb = (const float*)d_in[7];
    const float* smul = (const float*)d_in[8];
    float* out = (float*)d_out;

    char* ws = (char*)d_ws;
    unsigned short* xb = (unsigned short*)(ws + 0);                 // 16777216 B
    unsigned short* w1b = (unsigned short*)(ws + 16777216);         // 6291456
    unsigned short* w2b = (unsigned short*)(ws + 23068672);         // 2097152
    float* biascat = (float*)(ws + 25165824);                       // 12288
    unsigned short* qkvb = (unsigned short*)(ws + 25178112);        // 50331648
    unsigned short* Qb = (unsigned short*)(ws + 75509760);          // 16777216
    unsigned short* Kb = (unsigned short*)(ws + 92286976);          // 16777216
    unsigned short* Vtb = (unsigned short*)(ws + 109064192);        // 16777216
    unsigned short* attb = (unsigned short*)(ws + 125841408);       // 16777216
    if (ws_size < 142618624) return;

    int n4;
    n4 = BB * LL * CC / 4;
    k_f2bf<<<(n4 + 255) / 256, 256, 0, stream>>>((const float4*)x, (ushort4*)xb, n4);
    n4 = 3 * CC * CC / 4;
    k_f2bf<<<(n4 + 255) / 256, 256, 0, stream>>>((const float4*)w1, (ushort4*)w1b, n4);
    n4 = CC * CC / 4;
    k_f2bf<<<(n4 + 255) / 256, 256, 0, stream>>>((const float4*)w2, (ushort4*)w2b, n4);
    k_biascat<<<12, 256, 0, stream>>>(qb, vb, biascat);

    k_gemm_bt<unsigned short><<<(8192 / 128) * (3072 / 128), 256, 0, stream>>>(
        xb, w1b, biascat, qkvb, BB * LL, 3 * CC, CC);

    k_qknorm<<<BB * LL * HH / 4, 256, 0, stream>>>(qkvb, rope, smul, Qb, Kb);
    k_vtrans<<<BB * HH * (LL / 64), 256, 0, stream>>>(qkvb, Vtb);
    k_attn<<<512, 256, 0, stream>>>(Qb, Kb, Vtb, attb);

    k_gemm_bt<float><<<(8192 / 128) * (1024 / 128), 256, 0, stream>>>(
        attb, w2b, pb, out, BB * LL, CC, CC);
}

// Round 13
// 330.828 us; speedup vs baseline: 1.4948x; 1.0089x over previous
//
#include <hip/hip_runtime.h>
#include <hip/hip_bf16.h>

#define BB 4
#define LL 2048
#define CC 1024
#define HH 16
#define DD 64
#define HALFD 32

typedef short bf16x8 __attribute__((ext_vector_type(8)));
typedef short bf16x4 __attribute__((ext_vector_type(4)));
typedef float f32x4 __attribute__((ext_vector_type(4)));

#if defined(__has_builtin)
#if __has_builtin(__builtin_amdgcn_mfma_f32_16x16x16bf16_1k)
#define HAVE_MFMA16 1
#endif
#endif

__device__ __forceinline__ float bf2f(unsigned short u) {
    union { unsigned int i; float f; } x; x.i = ((unsigned int)u) << 16; return x.f;
}
__device__ __forceinline__ unsigned short f2bf(float f) {
    union { float f; unsigned int i; } x; x.f = f;
    return (unsigned short)((x.i + 0x7fffu + ((x.i >> 16) & 1u)) >> 16);
}
__device__ __forceinline__ unsigned int cvtpk_bf16(float lo, float hi) {
    unsigned int r;
    asm("v_cvt_pk_bf16_f32 %0, %1, %2" : "=v"(r) : "v"(lo), "v"(hi));
    return r;
}
__device__ __forceinline__ float exp2v(float x) {
    float r;
    asm("v_exp_f32 %0, %1" : "=v"(r) : "v"(x));
    return r;
}
__device__ __forceinline__ void gload_lds16(const void* g, void* l) {
    __builtin_amdgcn_global_load_lds(
        (const __attribute__((address_space(1))) unsigned int*)g,
        (__attribute__((address_space(3))) unsigned int*)l, 16, 0, 0);
}

// ---------------- prep: fp32 -> bf16 ----------------
__global__ void k_f2bf(const float4* __restrict__ in, ushort4* __restrict__ out, int n4) {
    int i = blockIdx.x * blockDim.x + threadIdx.x;
    if (i < n4) {
        float4 v = in[i];
        ushort4 o;
        o.x = f2bf(v.x); o.y = f2bf(v.y); o.z = f2bf(v.z); o.w = f2bf(v.w);
        out[i] = o;
    }
}

__global__ void k_biascat(const float* __restrict__ qb, const float* __restrict__ vb,
                          float* __restrict__ out) {
    int i = blockIdx.x * blockDim.x + threadIdx.x;
    if (i < 3 * CC) out[i] = (i < CC) ? qb[i] : (i < 2 * CC ? 0.f : vb[i - 2 * CC]);
}

// ---------------- GEMM: C[M,N] = A[M,K] * Bt[N,K]^T + bias[N] ----------------
// 128x128 tile, BK=32, 4 waves, global_load_lds(16B) staging into linear LDS (m97).
// XCD-bijective tile swizzle (grid%8==0): contiguous logical tiles per XCD -> L2 reuse.
template <typename OutT>
__global__ __launch_bounds__(256) void k_gemm_bt(
    const unsigned short* __restrict__ A, const unsigned short* __restrict__ Bt,
    const float* __restrict__ bias, OutT* __restrict__ Cout, int M, int N, int K) {
    __shared__ unsigned short As[128][32];
    __shared__ unsigned short Bs[128][32];
    int nwg = gridDim.x;
    int cpx = nwg >> 3;
    int swz = (blockIdx.x & 7) * cpx + (blockIdx.x >> 3);
    int nT = N >> 7;
    int tM = (swz / nT) << 7;
    int tN = (swz % nT) << 7;
    int t = threadIdx.x;
    int lane = t & 63, wid = t >> 6;
    int wr = (wid >> 1) * 64, wc = (wid & 1) * 64;
    int c = lane & 15, g = lane >> 4;

    const unsigned short* gA = A + (size_t)(tM + wid * 32 + (lane >> 2)) * K + (lane & 3) * 8;
    const unsigned short* gB = Bt + (size_t)(tN + wid * 32 + (lane >> 2)) * K + (lane & 3) * 8;
    unsigned short* lA0 = &As[wid * 32][0];
    unsigned short* lA1 = &As[wid * 32 + 16][0];
    unsigned short* lB0 = &Bs[wid * 32][0];
    unsigned short* lB1 = &Bs[wid * 32 + 16][0];
    size_t r16 = (size_t)16 * K;

    f32x4 acc[4][4];
#pragma unroll
    for (int i = 0; i < 4; i++)
#pragma unroll
        for (int j = 0; j < 4; j++) acc[i][j] = (f32x4){0.f, 0.f, 0.f, 0.f};

    for (int k0 = 0; k0 < K; k0 += 32) {
        __syncthreads();
        gload_lds16(gA + k0, lA0);
        gload_lds16(gA + k0 + r16, lA1);
        gload_lds16(gB + k0, lB0);
        gload_lds16(gB + k0 + r16, lB1);
        __syncthreads();
        bf16x8 af[4], bfr[4];
#pragma unroll
        for (int fm = 0; fm < 4; fm++) af[fm] = *(const bf16x8*)&As[wr + fm * 16 + c][g * 8];
#pragma unroll
        for (int fn = 0; fn < 4; fn++) bfr[fn] = *(const bf16x8*)&Bs[wc + fn * 16 + c][g * 8];
#pragma unroll
        for (int fm = 0; fm < 4; fm++)
#pragma unroll
            for (int fn = 0; fn < 4; fn++)
                acc[fm][fn] = __builtin_amdgcn_mfma_f32_16x16x32_bf16(af[fm], bfr[fn],
                                                                      acc[fm][fn], 0, 0, 0);
    }
#pragma unroll
    for (int fm = 0; fm < 4; fm++) {
#pragma unroll
        for (int fn = 0; fn < 4; fn++) {
            int col = tN + wc + fn * 16 + c;
            float bv = bias[col];
#pragma unroll
            for (int r = 0; r < 4; r++) {
                int row = tM + wr + fm * 16 + g * 4 + r;
                float v = acc[fm][fn][r] + bv;
                if constexpr (sizeof(OutT) == 2)
                    Cout[(size_t)row * N + col] = f2bf(v);
                else
                    Cout[(size_t)row * N + col] = v;
            }
        }
    }
}

// ---------------- Q/K: l2norm + scale(+log2e) + RoPE, layout (B,H,L,D) bf16 ----------------
__global__ __launch_bounds__(256) void k_qknorm(
    const unsigned short* __restrict__ qkv, const float* __restrict__ rope,
    const float* __restrict__ smul, unsigned short* __restrict__ Q,
    unsigned short* __restrict__ Ko) {
    int wid = threadIdx.x >> 6, lane = threadIdx.x & 63;
    long rowid = (long)blockIdx.x * 4 + wid;  // (b,l,h), h fastest
    int h = rowid & 15;
    long t2 = rowid >> 4;
    int l = t2 & 2047;
    int b = (int)(t2 >> 11);
    size_t base = ((size_t)(b * LL + l) * 3) * CC + h * 64 + lane;
    float q = bf2f(qkv[base]);
    float k = bf2f(qkv[base + CC]);
    float sq = q * q, sk = k * k;
#pragma unroll
    for (int m = 32; m >= 1; m >>= 1) {
        sq += __shfl_xor(sq, m);
        sk += __shfl_xor(sk, m);
    }
    // fold log2(e) into the q scale: softmax then uses exp2 directly (exact cancellation)
    float sm = expf(fminf(smul[h], 4.6051701859880913680f)) * 1.4426950408889634f;
    q = q / fmaxf(sqrtf(sq), 1e-12f) * sm;
    k = k / fmaxf(sqrtf(sk), 1e-12f);
    int j = lane >> 1;
    float cs = rope[((size_t)(b * 2) * LL + l) * HALFD + j];
    float sn = rope[((size_t)(b * 2 + 1) * LL + l) * HALFD + j];
    float qp = __shfl_xor(q, 1), kp = __shfl_xor(k, 1);
    float qn = (lane & 1) ? (qp * sn + q * cs) : (q * cs - qp * sn);
    float kn = (lane & 1) ? (kp * sn + k * cs) : (k * cs - kp * sn);
    size_t ob = ((size_t)(b * HH + h) * LL + l) * 64 + lane;
    Q[ob] = f2bf(qn);
    Ko[ob] = f2bf(kn);
}

// ---------------- V transpose: (B,L,H,D) slice of qkv -> Vt (B,H,D,L) bf16 ----------------
__global__ __launch_bounds__(256) void k_vtrans(const unsigned short* __restrict__ qkv,
                                               unsigned short* __restrict__ Vt) {
    __shared__ unsigned short tile[64][65];
    int bid = blockIdx.x;
    int lb = bid & 31;  // L/64
    int bh = bid >> 5;
    int h = bh & 15, b = bh >> 4;
    int t = threadIdx.x;
    for (int i = t; i < 4096; i += 256) {
        int row = i >> 6, dd = i & 63;
        tile[row][dd] = qkv[((size_t)(b * LL + lb * 64 + row) * 3 + 2) * CC + h * 64 + dd];
    }
    __syncthreads();
    for (int i = t; i < 4096; i += 256) {
        int dd = i >> 6, l2 = i & 63;
        Vt[((size_t)bh * 64 + dd) * LL + lb * 64 + l2] = tile[l2][dd];
    }
}

// ---------------- causal flash attention: balanced strip-pair blocks, two phases ----------------
// EXACT round-9 passing structure (512 blocks = 64 heads x 8 pairs; block does strips
// j and 15-j; wave = 32 rows; per-wave k-loop; KVBLK=64; swapped-QK^T; defer-max;
// exp2 softmax; cvtpk; register-direct PV). ONLY change vs round 9: s_setprio calls
// removed — they are side-effecting instructions that pinned instruction order and
// serialized the two independent qt dependency chains (m190: setprio hurts lockstep
// structures); without them the compiler can interleave qt=0/qt=1 chains for ~2x ILP.
__global__ __launch_bounds__(256) void k_attn(
    const unsigned short* __restrict__ Q, const unsigned short* __restrict__ K,
    const unsigned short* __restrict__ Vt, unsigned short* __restrict__ Out) {
    int lane = threadIdx.x & 63, wid = threadIdx.x >> 6;
    int c = lane & 15, g = lane >> 4;
    int bid = blockIdx.x;
    int xcd = bid & 7;
    int hgrp = (bid >> 3) & 7;
    int jp = bid >> 6;             // 0..7: pair index
    int bh = hgrp * 8 + xcd;       // 8 heads per XCD cluster -> K/V fits one L2
    const unsigned short* Qh = Q + (size_t)bh * LL * 64;
    const unsigned short* Kh = K + (size_t)bh * LL * 64;
    const unsigned short* Vh = Vt + (size_t)bh * 64 * LL;
    int b = bh >> 4, h = bh & 15;

#ifndef HAVE_MFMA16
    int srcA = 32 * (g & 1) + c;
    int srcB = srcA + 16;
#endif

#pragma unroll 1
    for (int ph = 0; ph < 2; ++ph) {
        int strip = ph ? (15 - jp) : jp;
        int qb = strip * 128 + wid * 32;

        bf16x8 qf[2][2];
#pragma unroll
        for (int qt = 0; qt < 2; qt++)
#pragma unroll
            for (int ch = 0; ch < 2; ch++)
                qf[qt][ch] =
                    *(const bf16x8*)&Qh[(size_t)(qb + qt * 16 + c) * 64 + ch * 32 + g * 8];

        f32x4 acc[2][4];  // [qt][dtile] of out^T: col=q=c, row=d=4g+r
#pragma unroll
        for (int qt = 0; qt < 2; qt++)
#pragma unroll
            for (int dt = 0; dt < 4; dt++) acc[qt][dt] = (f32x4){0.f, 0.f, 0.f, 0.f};
        float m_[2] = {-1e30f, -1e30f}, l_[2] = {0.f, 0.f};

#pragma unroll 1
        for (int kt = 0; kt < qb + 32; kt += 64) {
            bf16x8 kf[4][2];
#pragma unroll
            for (int kt2 = 0; kt2 < 4; kt2++)
#pragma unroll
                for (int ch = 0; ch < 2; ch++)
                    kf[kt2][ch] =
                        *(const bf16x8*)&Kh[(size_t)(kt + kt2 * 16 + c) * 64 + ch * 32 + g * 8];
#ifdef HAVE_MFMA16
            bf16x4 vf[4][4];  // [dt][kt2]: row=d=dt*16+c, kk(k)=4g+e
#pragma unroll
            for (int dt = 0; dt < 4; dt++)
#pragma unroll
                for (int kt2 = 0; kt2 < 4; kt2++)
                    vf[dt][kt2] =
                        *(const bf16x4*)&Vh[(size_t)(dt * 16 + c) * LL + kt + kt2 * 16 + 4 * g];
#else
            bf16x8 vf8[4][2];
#pragma unroll
            for (int dt = 0; dt < 4; dt++)
#pragma unroll
                for (int hf = 0; hf < 2; hf++)
                    vf8[dt][hf] =
                        *(const bf16x8*)&Vh[(size_t)(dt * 16 + c) * LL + kt + hf * 32 + 8 * g];
#endif
#pragma unroll
            for (int qt = 0; qt < 2; qt++) {
                int qtb = qb + qt * 16;
                if (kt > qtb + 15) continue;  // this tile finished (wave-uniform)
                int qrow = qtb + c;
                f32x4 sv[4];
#pragma unroll
                for (int kt2 = 0; kt2 < 4; kt2++) {
                    sv[kt2] = (f32x4){0.f, 0.f, 0.f, 0.f};
                    sv[kt2] = __builtin_amdgcn_mfma_f32_16x16x32_bf16(kf[kt2][0], qf[qt][0],
                                                                      sv[kt2], 0, 0, 0);
                    sv[kt2] = __builtin_amdgcn_mfma_f32_16x16x32_bf16(kf[kt2][1], qf[qt][1],
                                                                      sv[kt2], 0, 0, 0);
                }
                if (kt + 63 > qtb) {
#pragma unroll
                    for (int kt2 = 0; kt2 < 4; kt2++) {
                        if (kt + kt2 * 16 + 15 > qtb) {
#pragma unroll
                            for (int r = 0; r < 4; r++)
                                if (kt + kt2 * 16 + 4 * g + r > qrow) sv[kt2][r] = -1e9f;
                        }
                    }
                }
                float tm = fmaxf(fmaxf(fmaxf(sv[0][0], sv[0][1]), fmaxf(sv[0][2], sv[0][3])),
                                 fmaxf(fmaxf(sv[1][0], sv[1][1]), fmaxf(sv[1][2], sv[1][3])));
                float tm2 = fmaxf(fmaxf(fmaxf(sv[2][0], sv[2][1]), fmaxf(sv[2][2], sv[2][3])),
                                  fmaxf(fmaxf(sv[3][0], sv[3][1]), fmaxf(sv[3][2], sv[3][3])));
                tm = fmaxf(tm, tm2);
                tm = fmaxf(tm, __shfl_xor(tm, 16));
                tm = fmaxf(tm, __shfl_xor(tm, 32));
                // defer-max: logits bounded (|s*log2e| <= ~5.8) -> rescale fires ~once
                if (__any(tm > m_[qt] + 12.0f)) {
                    float mn = fmaxf(m_[qt], tm);
                    float scl = exp2v(m_[qt] - mn);
                    m_[qt] = mn;
                    l_[qt] *= scl;
#pragma unroll
                    for (int dt = 0; dt < 4; dt++) {
                        acc[qt][dt][0] *= scl; acc[qt][dt][1] *= scl;
                        acc[qt][dt][2] *= scl; acc[qt][dt][3] *= scl;
                    }
                }
                float p[4][4];
                float rs = 0.f;
#pragma unroll
                for (int kt2 = 0; kt2 < 4; kt2++)
#pragma unroll
                    for (int r = 0; r < 4; r++) {
                        p[kt2][r] = exp2v(sv[kt2][r] - m_[qt]);
                        rs += p[kt2][r];
                    }
                rs += __shfl_xor(rs, 16);
                rs += __shfl_xor(rs, 32);
                l_[qt] += rs;
#ifdef HAVE_MFMA16
                bf16x4 pbv[4];
#pragma unroll
                for (int kt2 = 0; kt2 < 4; kt2++) {
                    union { unsigned int w[2]; bf16x4 v; } pu;
                    pu.w[0] = cvtpk_bf16(p[kt2][0], p[kt2][1]);
                    pu.w[1] = cvtpk_bf16(p[kt2][2], p[kt2][3]);
                    pbv[kt2] = pu.v;
                }
#pragma unroll
                for (int dt = 0; dt < 4; dt++)
#pragma unroll
                    for (int kt2 = 0; kt2 < 4; kt2++)
                        acc[qt][dt] = __builtin_amdgcn_mfma_f32_16x16x16bf16_1k(
                            vf[dt][kt2], pbv[kt2], acc[qt][dt], 0, 0, 0);
#else
#pragma unroll
                for (int hf = 0; hf < 2; hf++) {
                    unsigned int A0 = cvtpk_bf16(p[2 * hf][0], p[2 * hf][1]);
                    unsigned int A1 = cvtpk_bf16(p[2 * hf][2], p[2 * hf][3]);
                    unsigned int B0 = cvtpk_bf16(p[2 * hf + 1][0], p[2 * hf + 1][1]);
                    unsigned int B1 = cvtpk_bf16(p[2 * hf + 1][2], p[2 * hf + 1][3]);
                    int t0a = __shfl((int)A0, srcA), t0b = __shfl((int)B0, srcA);
                    int t1a = __shfl((int)A1, srcA), t1b = __shfl((int)B1, srcA);
                    int t2a = __shfl((int)A0, srcB), t2b = __shfl((int)B0, srcB);
                    int t3a = __shfl((int)A1, srcB), t3b = __shfl((int)B1, srcB);
                    union { int w[4]; bf16x8 v; } u;
                    bool hi = (g & 2) != 0;
                    u.w[0] = hi ? t0b : t0a;
                    u.w[1] = hi ? t1b : t1a;
                    u.w[2] = hi ? t2b : t2a;
                    u.w[3] = hi ? t3b : t3a;
#pragma unroll
                    for (int dt = 0; dt < 4; dt++)
                        acc[qt][dt] = __builtin_amdgcn_mfma_f32_16x16x32_bf16(
                            vf8[dt][hf], u.v, acc[qt][dt], 0, 0, 0);
                }
#endif
            }
        }
        // epilogue: Out (B,L,C) bf16; lane writes d = dt*16 + 4g + r, q = qb+qt*16+c
#pragma unroll
        for (int qt = 0; qt < 2; qt++) {
            float inv = 1.f / l_[qt];
            int qg = qb + qt * 16 + c;
            size_t ob = ((size_t)b * LL + qg) * CC + h * 64;
#pragma unroll
            for (int dt = 0; dt < 4; dt++) {
                union { unsigned int w[2]; ushort4 v; } o;
                o.w[0] = cvtpk_bf16(acc[qt][dt][0] * inv, acc[qt][dt][1] * inv);
                o.w[1] = cvtpk_bf16(acc[qt][dt][2] * inv, acc[qt][dt][3] * inv);
                *(ushort4*)&Out[ob + dt * 16 + 4 * g] = o.v;
            }
        }
    }
}

extern "C" void kernel_launch(void* const* d_in, const int* in_sizes, int n_in,
                              void* d_out, int out_size, void* d_ws, size_t ws_size,
                              hipStream_t stream) {
    const float* x = (const float*)d_in[0];
    const float* rope = (const float*)d_in[2];
    const float* w1 = (const float*)d_in[3];
    const float* qb = (const float*)d_in[4];
    const float* vb = (const float*)d_in[5];
    const float* w2 = (const float*)d_in[6];
    const float* pb = (const float*)d_in[7];
    const float* smul = (const float*)d_in[8];
    float* out = (float*)d_out;

    char* ws = (char*)d_ws;
    unsigned short* xb = (unsigned short*)(ws + 0);                 // 16777216 B
    unsigned short* w1b = (unsigned short*)(ws + 16777216);         // 6291456
    unsigned short* w2b = (unsigned short*)(ws + 23068672);         // 2097152
    float* biascat = (float*)(ws + 25165824);                       // 12288
    unsigned short* qkvb = (unsigned short*)(ws + 25178112);        // 50331648
    unsigned short* Qb = (unsigned short*)(ws + 75509760);          // 16777216
    unsigned short* Kb = (unsigned short*)(ws + 92286976);          // 16777216
    unsigned short* Vtb = (unsigned short*)(ws + 109064192);        // 16777216
    unsigned short* attb = (unsigned short*)(ws + 125841408);       // 16777216
    if (ws_size < 142618624) return;

    int n4;
    n4 = BB * LL * CC / 4;
    k_f2bf<<<(n4 + 255) / 256, 256, 0, stream>>>((const float4*)x, (ushort4*)xb, n4);
    n4 = 3 * CC * CC / 4;
    k_f2bf<<<(n4 + 255) / 256, 256, 0, stream>>>((const float4*)w1, (ushort4*)w1b, n4);
    n4 = CC * CC / 4;
    k_f2bf<<<(n4 + 255) / 256, 256, 0, stream>>>((const float4*)w2, (ushort4*)w2b, n4);
    k_biascat<<<12, 256, 0, stream>>>(qb, vb, biascat);

    k_gemm_bt<unsigned short><<<(8192 / 128) * (3072 / 128), 256, 0, stream>>>(
        xb, w1b, biascat, qkvb, BB * LL, 3 * CC, CC);

    k_qknorm<<<BB * LL * HH / 4, 256, 0, stream>>>(qkvb, rope, smul, Qb, Kb);
    k_vtrans<<<BB * HH * (LL / 64), 256, 0, stream>>>(qkvb, Vtb);
    k_attn<<<512, 256, 0, stream>>>(Qb, Kb, Vtb, attb);

    k_gemm_bt<float><<<(8192 / 128) * (1024 / 128), 256, 0, stream>>>(
        attb, w2b, pb, out, BB * LL, CC, CC);
}

// Round 15
// 327.482 us; speedup vs baseline: 1.5101x; 1.0102x over previous
//
#include <hip/hip_runtime.h>
#include <hip/hip_bf16.h>

#define BB 4
#define LL 2048
#define CC 1024
#define HH 16
#define DD 64
#define HALFD 32

typedef short bf16x8 __attribute__((ext_vector_type(8)));
typedef short bf16x4 __attribute__((ext_vector_type(4)));
typedef float f32x4 __attribute__((ext_vector_type(4)));

#if defined(__has_builtin)
#if __has_builtin(__builtin_amdgcn_mfma_f32_16x16x16bf16_1k)
#define HAVE_MFMA16 1
#endif
#endif

__device__ __forceinline__ float bf2f(unsigned short u) {
    union { unsigned int i; float f; } x; x.i = ((unsigned int)u) << 16; return x.f;
}
__device__ __forceinline__ unsigned short f2bf(float f) {
    union { float f; unsigned int i; } x; x.f = f;
    return (unsigned short)((x.i + 0x7fffu + ((x.i >> 16) & 1u)) >> 16);
}
__device__ __forceinline__ unsigned int cvtpk_bf16(float lo, float hi) {
    unsigned int r;
    asm("v_cvt_pk_bf16_f32 %0, %1, %2" : "=v"(r) : "v"(lo), "v"(hi));
    return r;
}
__device__ __forceinline__ float exp2v(float x) {
    float r;
    asm("v_exp_f32 %0, %1" : "=v"(r) : "v"(x));
    return r;
}
__device__ __forceinline__ void gload_lds16(const void* g, void* l) {
    __builtin_amdgcn_global_load_lds(
        (const __attribute__((address_space(1))) unsigned int*)g,
        (__attribute__((address_space(3))) unsigned int*)l, 16, 0, 0);
}

// ---------------- prep: fp32 -> bf16 ----------------
__global__ void k_f2bf(const float4* __restrict__ in, ushort4* __restrict__ out, int n4) {
    int i = blockIdx.x * blockDim.x + threadIdx.x;
    if (i < n4) {
        float4 v = in[i];
        ushort4 o;
        o.x = f2bf(v.x); o.y = f2bf(v.y); o.z = f2bf(v.z); o.w = f2bf(v.w);
        out[i] = o;
    }
}

__global__ void k_biascat(const float* __restrict__ qb, const float* __restrict__ vb,
                          float* __restrict__ out) {
    int i = blockIdx.x * blockDim.x + threadIdx.x;
    if (i < 3 * CC) out[i] = (i < CC) ? qb[i] : (i < 2 * CC ? 0.f : vb[i - 2 * CC]);
}

// ---------------- GEMM: C[M,N] = A[M,K] * Bt[N,K]^T + bias[N] ----------------
// 128x128 tile, 4 waves, global_load_lds(16B) staging (m97 pattern).
// K-step 64 via TWO independent [128][32] LDS buffer sets (each the proven 64B-row
// layout, 2-way-conflict-free): one barrier pair covers 8 DMAs + 32 MFMAs, halving
// barrier-drain stalls vs BK=32. XCD-bijective tile swizzle (grid%8==0) for L2 reuse.
template <typename OutT>
__global__ __launch_bounds__(256) void k_gemm_bt(
    const unsigned short* __restrict__ A, const unsigned short* __restrict__ Bt,
    const float* __restrict__ bias, OutT* __restrict__ Cout, int M, int N, int K) {
    __shared__ unsigned short As0[128][32];
    __shared__ unsigned short As1[128][32];
    __shared__ unsigned short Bs0[128][32];
    __shared__ unsigned short Bs1[128][32];
    int nwg = gridDim.x;
    int cpx = nwg >> 3;
    int swz = (blockIdx.x & 7) * cpx + (blockIdx.x >> 3);
    int nT = N >> 7;
    int tM = (swz / nT) << 7;
    int tN = (swz % nT) << 7;
    int t = threadIdx.x;
    int lane = t & 63, wid = t >> 6;
    int wr = (wid >> 1) * 64, wc = (wid & 1) * 64;
    int c = lane & 15, g = lane >> 4;

    const unsigned short* gA = A + (size_t)(tM + wid * 32 + (lane >> 2)) * K + (lane & 3) * 8;
    const unsigned short* gB = Bt + (size_t)(tN + wid * 32 + (lane >> 2)) * K + (lane & 3) * 8;
    unsigned short* a00 = &As0[wid * 32][0];
    unsigned short* a01 = &As0[wid * 32 + 16][0];
    unsigned short* a10 = &As1[wid * 32][0];
    unsigned short* a11 = &As1[wid * 32 + 16][0];
    unsigned short* b00 = &Bs0[wid * 32][0];
    unsigned short* b01 = &Bs0[wid * 32 + 16][0];
    unsigned short* b10 = &Bs1[wid * 32][0];
    unsigned short* b11 = &Bs1[wid * 32 + 16][0];
    size_t r16 = (size_t)16 * K;

    f32x4 acc[4][4];
#pragma unroll
    for (int i = 0; i < 4; i++)
#pragma unroll
        for (int j = 0; j < 4; j++) acc[i][j] = (f32x4){0.f, 0.f, 0.f, 0.f};

    for (int k0 = 0; k0 < K; k0 += 64) {
        __syncthreads();
        gload_lds16(gA + k0, a00);
        gload_lds16(gA + k0 + r16, a01);
        gload_lds16(gB + k0, b00);
        gload_lds16(gB + k0 + r16, b01);
        gload_lds16(gA + k0 + 32, a10);
        gload_lds16(gA + k0 + 32 + r16, a11);
        gload_lds16(gB + k0 + 32, b10);
        gload_lds16(gB + k0 + 32 + r16, b11);
        __syncthreads();
        bf16x8 af[4], bfr[4];
#pragma unroll
        for (int fm = 0; fm < 4; fm++) af[fm] = *(const bf16x8*)&As0[wr + fm * 16 + c][g * 8];
#pragma unroll
        for (int fn = 0; fn < 4; fn++) bfr[fn] = *(const bf16x8*)&Bs0[wc + fn * 16 + c][g * 8];
#pragma unroll
        for (int fm = 0; fm < 4; fm++)
#pragma unroll
            for (int fn = 0; fn < 4; fn++)
                acc[fm][fn] = __builtin_amdgcn_mfma_f32_16x16x32_bf16(af[fm], bfr[fn],
                                                                      acc[fm][fn], 0, 0, 0);
#pragma unroll
        for (int fm = 0; fm < 4; fm++) af[fm] = *(const bf16x8*)&As1[wr + fm * 16 + c][g * 8];
#pragma unroll
        for (int fn = 0; fn < 4; fn++) bfr[fn] = *(const bf16x8*)&Bs1[wc + fn * 16 + c][g * 8];
#pragma unroll
        for (int fm = 0; fm < 4; fm++)
#pragma unroll
            for (int fn = 0; fn < 4; fn++)
                acc[fm][fn] = __builtin_amdgcn_mfma_f32_16x16x32_bf16(af[fm], bfr[fn],
                                                                      acc[fm][fn], 0, 0, 0);
    }
#pragma unroll
    for (int fm = 0; fm < 4; fm++) {
#pragma unroll
        for (int fn = 0; fn < 4; fn++) {
            int col = tN + wc + fn * 16 + c;
            float bv = bias[col];
#pragma unroll
            for (int r = 0; r < 4; r++) {
                int row = tM + wr + fm * 16 + g * 4 + r;
                float v = acc[fm][fn][r] + bv;
                if constexpr (sizeof(OutT) == 2)
                    Cout[(size_t)row * N + col] = f2bf(v);
                else
                    Cout[(size_t)row * N + col] = v;
            }
        }
    }
}

// ---------------- Q/K: l2norm + scale(+log2e) + RoPE, layout (B,H,L,D) bf16 ----------------
__global__ __launch_bounds__(256) void k_qknorm(
    const unsigned short* __restrict__ qkv, const float* __restrict__ rope,
    const float* __restrict__ smul, unsigned short* __restrict__ Q,
    unsigned short* __restrict__ Ko) {
    int wid = threadIdx.x >> 6, lane = threadIdx.x & 63;
    long rowid = (long)blockIdx.x * 4 + wid;  // (b,l,h), h fastest
    int h = rowid & 15;
    long t2 = rowid >> 4;
    int l = t2 & 2047;
    int b = (int)(t2 >> 11);
    size_t base = ((size_t)(b * LL + l) * 3) * CC + h * 64 + lane;
    float q = bf2f(qkv[base]);
    float k = bf2f(qkv[base + CC]);
    float sq = q * q, sk = k * k;
#pragma unroll
    for (int m = 32; m >= 1; m >>= 1) {
        sq += __shfl_xor(sq, m);
        sk += __shfl_xor(sk, m);
    }
    // fold log2(e) into the q scale: softmax then uses exp2 directly (exact cancellation)
    float sm = expf(fminf(smul[h], 4.6051701859880913680f)) * 1.4426950408889634f;
    q = q / fmaxf(sqrtf(sq), 1e-12f) * sm;
    k = k / fmaxf(sqrtf(sk), 1e-12f);
    int j = lane >> 1;
    float cs = rope[((size_t)(b * 2) * LL + l) * HALFD + j];
    float sn = rope[((size_t)(b * 2 + 1) * LL + l) * HALFD + j];
    float qp = __shfl_xor(q, 1), kp = __shfl_xor(k, 1);
    float qn = (lane & 1) ? (qp * sn + q * cs) : (q * cs - qp * sn);
    float kn = (lane & 1) ? (kp * sn + k * cs) : (k * cs - kp * sn);
    size_t ob = ((size_t)(b * HH + h) * LL + l) * 64 + lane;
    Q[ob] = f2bf(qn);
    Ko[ob] = f2bf(kn);
}

// ---------------- V transpose: (B,L,H,D) slice of qkv -> Vt (B,H,D,L) bf16 ----------------
__global__ __launch_bounds__(256) void k_vtrans(const unsigned short* __restrict__ qkv,
                                               unsigned short* __restrict__ Vt) {
    __shared__ unsigned short tile[64][65];
    int bid = blockIdx.x;
    int lb = bid & 31;  // L/64
    int bh = bid >> 5;
    int h = bh & 15, b = bh >> 4;
    int t = threadIdx.x;
    for (int i = t; i < 4096; i += 256) {
        int row = i >> 6, dd = i & 63;
        tile[row][dd] = qkv[((size_t)(b * LL + lb * 64 + row) * 3 + 2) * CC + h * 64 + dd];
    }
    __syncthreads();
    for (int i = t; i < 4096; i += 256) {
        int dd = i >> 6, l2 = i & 63;
        Vt[((size_t)bh * 64 + dd) * LL + lb * 64 + l2] = tile[l2][dd];
    }
}

// ---------------- causal flash attention: balanced strip-pair blocks, two phases ----------------
// FROZEN: byte-identical to the round-13 PASSING kernel (512 blocks = 64 heads x 8
// pairs; block does strips j and 15-j; wave = 32 rows; per-wave k-loop; KVBLK=64;
// swapped-QK^T; defer-max; exp2 softmax; cvtpk; register-direct PV; no setprio).
// Six rounds of body edits (r6/r8/r10/r11/r12/r14) all produced NaN through an
// unobservable codegen-level mechanism; this compilation is empirically golden.
__global__ __launch_bounds__(256) void k_attn(
    const unsigned short* __restrict__ Q, const unsigned short* __restrict__ K,
    const unsigned short* __restrict__ Vt, unsigned short* __restrict__ Out) {
    int lane = threadIdx.x & 63, wid = threadIdx.x >> 6;
    int c = lane & 15, g = lane >> 4;
    int bid = blockIdx.x;
    int xcd = bid & 7;
    int hgrp = (bid >> 3) & 7;
    int jp = bid >> 6;             // 0..7: pair index
    int bh = hgrp * 8 + xcd;       // 8 heads per XCD cluster -> K/V fits one L2
    const unsigned short* Qh = Q + (size_t)bh * LL * 64;
    const unsigned short* Kh = K + (size_t)bh * LL * 64;
    const unsigned short* Vh = Vt + (size_t)bh * 64 * LL;
    int b = bh >> 4, h = bh & 15;

#ifndef HAVE_MFMA16
    int srcA = 32 * (g & 1) + c;
    int srcB = srcA + 16;
#endif

#pragma unroll 1
    for (int ph = 0; ph < 2; ++ph) {
        int strip = ph ? (15 - jp) : jp;
        int qb = strip * 128 + wid * 32;

        bf16x8 qf[2][2];
#pragma unroll
        for (int qt = 0; qt < 2; qt++)
#pragma unroll
            for (int ch = 0; ch < 2; ch++)
                qf[qt][ch] =
                    *(const bf16x8*)&Qh[(size_t)(qb + qt * 16 + c) * 64 + ch * 32 + g * 8];

        f32x4 acc[2][4];  // [qt][dtile] of out^T: col=q=c, row=d=4g+r
#pragma unroll
        for (int qt = 0; qt < 2; qt++)
#pragma unroll
            for (int dt = 0; dt < 4; dt++) acc[qt][dt] = (f32x4){0.f, 0.f, 0.f, 0.f};
        float m_[2] = {-1e30f, -1e30f}, l_[2] = {0.f, 0.f};

#pragma unroll 1
        for (int kt = 0; kt < qb + 32; kt += 64) {
            bf16x8 kf[4][2];
#pragma unroll
            for (int kt2 = 0; kt2 < 4; kt2++)
#pragma unroll
                for (int ch = 0; ch < 2; ch++)
                    kf[kt2][ch] =
                        *(const bf16x8*)&Kh[(size_t)(kt + kt2 * 16 + c) * 64 + ch * 32 + g * 8];
#ifdef HAVE_MFMA16
            bf16x4 vf[4][4];  // [dt][kt2]: row=d=dt*16+c, kk(k)=4g+e
#pragma unroll
            for (int dt = 0; dt < 4; dt++)
#pragma unroll
                for (int kt2 = 0; kt2 < 4; kt2++)
                    vf[dt][kt2] =
                        *(const bf16x4*)&Vh[(size_t)(dt * 16 + c) * LL + kt + kt2 * 16 + 4 * g];
#else
            bf16x8 vf8[4][2];
#pragma unroll
            for (int dt = 0; dt < 4; dt++)
#pragma unroll
                for (int hf = 0; hf < 2; hf++)
                    vf8[dt][hf] =
                        *(const bf16x8*)&Vh[(size_t)(dt * 16 + c) * LL + kt + hf * 32 + 8 * g];
#endif
#pragma unroll
            for (int qt = 0; qt < 2; qt++) {
                int qtb = qb + qt * 16;
                if (kt > qtb + 15) continue;  // this tile finished (wave-uniform)
                int qrow = qtb + c;
                f32x4 sv[4];
#pragma unroll
                for (int kt2 = 0; kt2 < 4; kt2++) {
                    sv[kt2] = (f32x4){0.f, 0.f, 0.f, 0.f};
                    sv[kt2] = __builtin_amdgcn_mfma_f32_16x16x32_bf16(kf[kt2][0], qf[qt][0],
                                                                      sv[kt2], 0, 0, 0);
                    sv[kt2] = __builtin_amdgcn_mfma_f32_16x16x32_bf16(kf[kt2][1], qf[qt][1],
                                                                      sv[kt2], 0, 0, 0);
                }
                if (kt + 63 > qtb) {
#pragma unroll
                    for (int kt2 = 0; kt2 < 4; kt2++) {
                        if (kt + kt2 * 16 + 15 > qtb) {
#pragma unroll
                            for (int r = 0; r < 4; r++)
                                if (kt + kt2 * 16 + 4 * g + r > qrow) sv[kt2][r] = -1e9f;
                        }
                    }
                }
                float tm = fmaxf(fmaxf(fmaxf(sv[0][0], sv[0][1]), fmaxf(sv[0][2], sv[0][3])),
                                 fmaxf(fmaxf(sv[1][0], sv[1][1]), fmaxf(sv[1][2], sv[1][3])));
                float tm2 = fmaxf(fmaxf(fmaxf(sv[2][0], sv[2][1]), fmaxf(sv[2][2], sv[2][3])),
                                  fmaxf(fmaxf(sv[3][0], sv[3][1]), fmaxf(sv[3][2], sv[3][3])));
                tm = fmaxf(tm, tm2);
                tm = fmaxf(tm, __shfl_xor(tm, 16));
                tm = fmaxf(tm, __shfl_xor(tm, 32));
                // defer-max: logits bounded (|s*log2e| <= ~5.8) -> rescale fires ~once
                if (__any(tm > m_[qt] + 12.0f)) {
                    float mn = fmaxf(m_[qt], tm);
                    float scl = exp2v(m_[qt] - mn);
                    m_[qt] = mn;
                    l_[qt] *= scl;
#pragma unroll
                    for (int dt = 0; dt < 4; dt++) {
                        acc[qt][dt][0] *= scl; acc[qt][dt][1] *= scl;
                        acc[qt][dt][2] *= scl; acc[qt][dt][3] *= scl;
                    }
                }
                float p[4][4];
                float rs = 0.f;
#pragma unroll
                for (int kt2 = 0; kt2 < 4; kt2++)
#pragma unroll
                    for (int r = 0; r < 4; r++) {
                        p[kt2][r] = exp2v(sv[kt2][r] - m_[qt]);
                        rs += p[kt2][r];
                    }
                rs += __shfl_xor(rs, 16);
                rs += __shfl_xor(rs, 32);
                l_[qt] += rs;
#ifdef HAVE_MFMA16
                bf16x4 pbv[4];
#pragma unroll
                for (int kt2 = 0; kt2 < 4; kt2++) {
                    union { unsigned int w[2]; bf16x4 v; } pu;
                    pu.w[0] = cvtpk_bf16(p[kt2][0], p[kt2][1]);
                    pu.w[1] = cvtpk_bf16(p[kt2][2], p[kt2][3]);
                    pbv[kt2] = pu.v;
                }
#pragma unroll
                for (int dt = 0; dt < 4; dt++)
#pragma unroll
                    for (int kt2 = 0; kt2 < 4; kt2++)
                        acc[qt][dt] = __builtin_amdgcn_mfma_f32_16x16x16bf16_1k(
                            vf[dt][kt2], pbv[kt2], acc[qt][dt], 0, 0, 0);
#else
#pragma unroll
                for (int hf = 0; hf < 2; hf++) {
                    unsigned int A0 = cvtpk_bf16(p[2 * hf][0], p[2 * hf][1]);
                    unsigned int A1 = cvtpk_bf16(p[2 * hf][2], p[2 * hf][3]);
                    unsigned int B0 = cvtpk_bf16(p[2 * hf + 1][0], p[2 * hf + 1][1]);
                    unsigned int B1 = cvtpk_bf16(p[2 * hf + 1][2], p[2 * hf + 1][3]);
                    int t0a = __shfl((int)A0, srcA), t0b = __shfl((int)B0, srcA);
                    int t1a = __shfl((int)A1, srcA), t1b = __shfl((int)B1, srcA);
                    int t2a = __shfl((int)A0, srcB), t2b = __shfl((int)B0, srcB);
                    int t3a = __shfl((int)A1, srcB), t3b = __shfl((int)B1, srcB);
                    union { int w[4]; bf16x8 v; } u;
                    bool hi = (g & 2) != 0;
                    u.w[0] = hi ? t0b : t0a;
                    u.w[1] = hi ? t1b : t1a;
                    u.w[2] = hi ? t2b : t2a;
                    u.w[3] = hi ? t3b : t3a;
#pragma unroll
                    for (int dt = 0; dt < 4; dt++)
                        acc[qt][dt] = __builtin_amdgcn_mfma_f32_16x16x32_bf16(
                            vf8[dt][hf], u.v, acc[qt][dt], 0, 0, 0);
                }
#endif
            }
        }
        // epilogue: Out (B,L,C) bf16; lane writes d = dt*16 + 4g + r, q = qb+qt*16+c
#pragma unroll
        for (int qt = 0; qt < 2; qt++) {
            float inv = 1.f / l_[qt];
            int qg = qb + qt * 16 + c;
            size_t ob = ((size_t)b * LL + qg) * CC + h * 64;
#pragma unroll
            for (int dt = 0; dt < 4; dt++) {
                union { unsigned int w[2]; ushort4 v; } o;
                o.w[0] = cvtpk_bf16(acc[qt][dt][0] * inv, acc[qt][dt][1] * inv);
                o.w[1] = cvtpk_bf16(acc[qt][dt][2] * inv, acc[qt][dt][3] * inv);
                *(ushort4*)&Out[ob + dt * 16 + 4 * g] = o.v;
            }
        }
    }
}

extern "C" void kernel_launch(void* const* d_in, const int* in_sizes, int n_in,
                              void* d_out, int out_size, void* d_ws, size_t ws_size,
                              hipStream_t stream) {
    const float* x = (const float*)d_in[0];
    const float* rope = (const float*)d_in[2];
    const float* w1 = (const float*)d_in[3];
    const float* qb = (const float*)d_in[4];
    const float* vb = (const float*)d_in[5];
    const float* w2 = (const float*)d_in[6];
    const float* pb = (const float*)d_in[7];
    const float* smul = (const float*)d_in[8];
    float* out = (float*)d_out;

    char* ws = (char*)d_ws;
    unsigned short* xb = (unsigned short*)(ws + 0);                 // 16777216 B
    unsigned short* w1b = (unsigned short*)(ws + 16777216);         // 6291456
    unsigned short* w2b = (unsigned short*)(ws + 23068672);         // 2097152
    float* biascat = (float*)(ws + 25165824);                       // 12288
    unsigned short* qkvb = (unsigned short*)(ws + 25178112);        // 50331648
    unsigned short* Qb = (unsigned short*)(ws + 75509760);          // 16777216
    unsigned short* Kb = (unsigned short*)(ws + 92286976);          // 16777216
    unsigned short* Vtb = (unsigned short*)(ws + 109064192);        // 16777216
    unsigned short* attb = (unsigned short*)(ws + 125841408);       // 16777216
    if (ws_size < 142618624) return;

    int n4;
    n4 = BB * LL * CC / 4;
    k_f2bf<<<(n4 + 255) / 256, 256, 0, stream>>>((const float4*)x, (ushort4*)xb, n4);
    n4 = 3 * CC * CC / 4;
    k_f2bf<<<(n4 + 255) / 256, 256, 0, stream>>>((const float4*)w1, (ushort4*)w1b, n4);
    n4 = CC * CC / 4;
    k_f2bf<<<(n4 + 255) / 256, 256, 0, stream>>>((const float4*)w2, (ushort4*)w2b, n4);
    k_biascat<<<12, 256, 0, stream>>>(qb, vb, biascat);

    k_gemm_bt<unsigned short><<<(8192 / 128) * (3072 / 128), 256, 0, stream>>>(
        xb, w1b, biascat, qkvb, BB * LL, 3 * CC, CC);

    k_qknorm<<<BB * LL * HH / 4, 256, 0, stream>>>(qkvb, rope, smul, Qb, Kb);
    k_vtrans<<<BB * HH * (LL / 64), 256, 0, stream>>>(qkvb, Vtb);
    k_attn<<<512, 256, 0, stream>>>(Qb, Kb, Vtb, attb);

    k_gemm_bt<float><<<(8192 / 128) * (1024 / 128), 256, 0, stream>>>(
        attb, w2b, pb, out, BB * LL, CC, CC);
}

// Round 16
// 322.157 us; speedup vs baseline: 1.5350x; 1.0165x over previous
//
#include <hip/hip_runtime.h>
#include <hip/hip_bf16.h>

#define BB 4
#define LL 2048
#define CC 1024
#define HH 16
#define DD 64
#define HALFD 32

typedef short bf16x8 __attribute__((ext_vector_type(8)));
typedef short bf16x4 __attribute__((ext_vector_type(4)));
typedef float f32x4 __attribute__((ext_vector_type(4)));

#if defined(__has_builtin)
#if __has_builtin(__builtin_amdgcn_mfma_f32_16x16x16bf16_1k)
#define HAVE_MFMA16 1
#endif
#endif

__device__ __forceinline__ float bf2f(unsigned short u) {
    union { unsigned int i; float f; } x; x.i = ((unsigned int)u) << 16; return x.f;
}
__device__ __forceinline__ unsigned short f2bf(float f) {
    union { float f; unsigned int i; } x; x.f = f;
    return (unsigned short)((x.i + 0x7fffu + ((x.i >> 16) & 1u)) >> 16);
}
__device__ __forceinline__ unsigned int cvtpk_bf16(float lo, float hi) {
    unsigned int r;
    asm("v_cvt_pk_bf16_f32 %0, %1, %2" : "=v"(r) : "v"(lo), "v"(hi));
    return r;
}
__device__ __forceinline__ float exp2v(float x) {
    float r;
    asm("v_exp_f32 %0, %1" : "=v"(r) : "v"(x));
    return r;
}
__device__ __forceinline__ void gload_lds16(const void* g, void* l) {
    __builtin_amdgcn_global_load_lds(
        (const __attribute__((address_space(1))) unsigned int*)g,
        (__attribute__((address_space(3))) unsigned int*)l, 16, 0, 0);
}

// ---------------- fused prep: all fp32->bf16 conversions + biascat in ONE launch ----------------
// Ranges (float4 units): [0,N1) -> x, [N1,N1+N2) -> w1, [N1+N2,N1+N2+N3) -> w2.
// Threads with flat id < 768 additionally write biascat (3072 floats as float4).
__global__ void k_prep(const float4* __restrict__ x, const float4* __restrict__ w1,
                       const float4* __restrict__ w2, const float* __restrict__ qb,
                       const float* __restrict__ vb, ushort4* __restrict__ xb,
                       ushort4* __restrict__ w1b, ushort4* __restrict__ w2b,
                       float4* __restrict__ biascat) {
    const int N1 = BB * LL * CC / 4;        // 2097152
    const int N2 = 3 * CC * CC / 4;         // 786432
    const int N3 = CC * CC / 4;             // 262144
    int i = blockIdx.x * blockDim.x + threadIdx.x;
    if (i < 768) {  // biascat: 3072 floats = 768 float4
        int e = i * 4;
        float4 o;
        o.x = (e + 0 < CC) ? qb[e + 0] : (e + 0 < 2 * CC ? 0.f : vb[e + 0 - 2 * CC]);
        o.y = (e + 1 < CC) ? qb[e + 1] : (e + 1 < 2 * CC ? 0.f : vb[e + 1 - 2 * CC]);
        o.z = (e + 2 < CC) ? qb[e + 2] : (e + 2 < 2 * CC ? 0.f : vb[e + 2 - 2 * CC]);
        o.w = (e + 3 < CC) ? qb[e + 3] : (e + 3 < 2 * CC ? 0.f : vb[e + 3 - 2 * CC]);
        biascat[i] = o;
    }
    float4 v;
    ushort4* dst;
    if (i < N1) {
        v = x[i];
        dst = &xb[i];
    } else if (i < N1 + N2) {
        v = w1[i - N1];
        dst = &w1b[i - N1];
    } else if (i < N1 + N2 + N3) {
        v = w2[i - N1 - N2];
        dst = &w2b[i - N1 - N2];
    } else {
        return;
    }
    ushort4 o;
    o.x = f2bf(v.x); o.y = f2bf(v.y); o.z = f2bf(v.z); o.w = f2bf(v.w);
    *dst = o;
}

// ---------------- GEMM: C[M,N] = A[M,K] * Bt[N,K]^T + bias[N] ----------------
// 128x128 tile, 4 waves, global_load_lds(16B) staging (m97 pattern).
// K-step 64 via TWO independent [128][32] LDS buffer sets (each the proven 64B-row
// layout, 2-way-conflict-free): one barrier pair covers 8 DMAs + 32 MFMAs.
// XCD-bijective tile swizzle (grid%8==0) for L2 reuse.
template <typename OutT>
__global__ __launch_bounds__(256) void k_gemm_bt(
    const unsigned short* __restrict__ A, const unsigned short* __restrict__ Bt,
    const float* __restrict__ bias, OutT* __restrict__ Cout, int M, int N, int K) {
    __shared__ unsigned short As0[128][32];
    __shared__ unsigned short As1[128][32];
    __shared__ unsigned short Bs0[128][32];
    __shared__ unsigned short Bs1[128][32];
    int nwg = gridDim.x;
    int cpx = nwg >> 3;
    int swz = (blockIdx.x & 7) * cpx + (blockIdx.x >> 3);
    int nT = N >> 7;
    int tM = (swz / nT) << 7;
    int tN = (swz % nT) << 7;
    int t = threadIdx.x;
    int lane = t & 63, wid = t >> 6;
    int wr = (wid >> 1) * 64, wc = (wid & 1) * 64;
    int c = lane & 15, g = lane >> 4;

    const unsigned short* gA = A + (size_t)(tM + wid * 32 + (lane >> 2)) * K + (lane & 3) * 8;
    const unsigned short* gB = Bt + (size_t)(tN + wid * 32 + (lane >> 2)) * K + (lane & 3) * 8;
    unsigned short* a00 = &As0[wid * 32][0];
    unsigned short* a01 = &As0[wid * 32 + 16][0];
    unsigned short* a10 = &As1[wid * 32][0];
    unsigned short* a11 = &As1[wid * 32 + 16][0];
    unsigned short* b00 = &Bs0[wid * 32][0];
    unsigned short* b01 = &Bs0[wid * 32 + 16][0];
    unsigned short* b10 = &Bs1[wid * 32][0];
    unsigned short* b11 = &Bs1[wid * 32 + 16][0];
    size_t r16 = (size_t)16 * K;

    f32x4 acc[4][4];
#pragma unroll
    for (int i = 0; i < 4; i++)
#pragma unroll
        for (int j = 0; j < 4; j++) acc[i][j] = (f32x4){0.f, 0.f, 0.f, 0.f};

    for (int k0 = 0; k0 < K; k0 += 64) {
        __syncthreads();
        gload_lds16(gA + k0, a00);
        gload_lds16(gA + k0 + r16, a01);
        gload_lds16(gB + k0, b00);
        gload_lds16(gB + k0 + r16, b01);
        gload_lds16(gA + k0 + 32, a10);
        gload_lds16(gA + k0 + 32 + r16, a11);
        gload_lds16(gB + k0 + 32, b10);
        gload_lds16(gB + k0 + 32 + r16, b11);
        __syncthreads();
        bf16x8 af[4], bfr[4];
#pragma unroll
        for (int fm = 0; fm < 4; fm++) af[fm] = *(const bf16x8*)&As0[wr + fm * 16 + c][g * 8];
#pragma unroll
        for (int fn = 0; fn < 4; fn++) bfr[fn] = *(const bf16x8*)&Bs0[wc + fn * 16 + c][g * 8];
#pragma unroll
        for (int fm = 0; fm < 4; fm++)
#pragma unroll
            for (int fn = 0; fn < 4; fn++)
                acc[fm][fn] = __builtin_amdgcn_mfma_f32_16x16x32_bf16(af[fm], bfr[fn],
                                                                      acc[fm][fn], 0, 0, 0);
#pragma unroll
        for (int fm = 0; fm < 4; fm++) af[fm] = *(const bf16x8*)&As1[wr + fm * 16 + c][g * 8];
#pragma unroll
        for (int fn = 0; fn < 4; fn++) bfr[fn] = *(const bf16x8*)&Bs1[wc + fn * 16 + c][g * 8];
#pragma unroll
        for (int fm = 0; fm < 4; fm++)
#pragma unroll
            for (int fn = 0; fn < 4; fn++)
                acc[fm][fn] = __builtin_amdgcn_mfma_f32_16x16x32_bf16(af[fm], bfr[fn],
                                                                      acc[fm][fn], 0, 0, 0);
    }
#pragma unroll
    for (int fm = 0; fm < 4; fm++) {
#pragma unroll
        for (int fn = 0; fn < 4; fn++) {
            int col = tN + wc + fn * 16 + c;
            float bv = bias[col];
#pragma unroll
            for (int r = 0; r < 4; r++) {
                int row = tM + wr + fm * 16 + g * 4 + r;
                float v = acc[fm][fn][r] + bv;
                if constexpr (sizeof(OutT) == 2)
                    Cout[(size_t)row * N + col] = f2bf(v);
                else
                    Cout[(size_t)row * N + col] = v;
            }
        }
    }
}

// ---------------- Q/K: l2norm + scale(+log2e) + RoPE, layout (B,H,L,D) bf16 ----------------
__global__ __launch_bounds__(256) void k_qknorm(
    const unsigned short* __restrict__ qkv, const float* __restrict__ rope,
    const float* __restrict__ smul, unsigned short* __restrict__ Q,
    unsigned short* __restrict__ Ko) {
    int wid = threadIdx.x >> 6, lane = threadIdx.x & 63;
    long rowid = (long)blockIdx.x * 4 + wid;  // (b,l,h), h fastest
    int h = rowid & 15;
    long t2 = rowid >> 4;
    int l = t2 & 2047;
    int b = (int)(t2 >> 11);
    size_t base = ((size_t)(b * LL + l) * 3) * CC + h * 64 + lane;
    float q = bf2f(qkv[base]);
    float k = bf2f(qkv[base + CC]);
    float sq = q * q, sk = k * k;
#pragma unroll
    for (int m = 32; m >= 1; m >>= 1) {
        sq += __shfl_xor(sq, m);
        sk += __shfl_xor(sk, m);
    }
    // fold log2(e) into the q scale: softmax then uses exp2 directly (exact cancellation)
    float sm = expf(fminf(smul[h], 4.6051701859880913680f)) * 1.4426950408889634f;
    q = q / fmaxf(sqrtf(sq), 1e-12f) * sm;
    k = k / fmaxf(sqrtf(sk), 1e-12f);
    int j = lane >> 1;
    float cs = rope[((size_t)(b * 2) * LL + l) * HALFD + j];
    float sn = rope[((size_t)(b * 2 + 1) * LL + l) * HALFD + j];
    float qp = __shfl_xor(q, 1), kp = __shfl_xor(k, 1);
    float qn = (lane & 1) ? (qp * sn + q * cs) : (q * cs - qp * sn);
    float kn = (lane & 1) ? (kp * sn + k * cs) : (k * cs - kp * sn);
    size_t ob = ((size_t)(b * HH + h) * LL + l) * 64 + lane;
    Q[ob] = f2bf(qn);
    Ko[ob] = f2bf(kn);
}

// ---------------- V transpose: (B,L,H,D) slice of qkv -> Vt (B,H,D,L) bf16 ----------------
__global__ __launch_bounds__(256) void k_vtrans(const unsigned short* __restrict__ qkv,
                                               unsigned short* __restrict__ Vt) {
    __shared__ unsigned short tile[64][65];
    int bid = blockIdx.x;
    int lb = bid & 31;  // L/64
    int bh = bid >> 5;
    int h = bh & 15, b = bh >> 4;
    int t = threadIdx.x;
    for (int i = t; i < 4096; i += 256) {
        int row = i >> 6, dd = i & 63;
        tile[row][dd] = qkv[((size_t)(b * LL + lb * 64 + row) * 3 + 2) * CC + h * 64 + dd];
    }
    __syncthreads();
    for (int i = t; i < 4096; i += 256) {
        int dd = i >> 6, l2 = i & 63;
        Vt[((size_t)bh * 64 + dd) * LL + lb * 64 + l2] = tile[l2][dd];
    }
}

// ---------------- causal flash attention: balanced strip-pair blocks, two phases ----------------
// FROZEN: byte-identical to the round-13 PASSING kernel (512 blocks = 64 heads x 8
// pairs; block does strips j and 15-j; wave = 32 rows; per-wave k-loop; KVBLK=64;
// swapped-QK^T; defer-max; exp2 softmax; cvtpk; register-direct PV; no setprio).
// Six rounds of body edits (r6/r8/r10/r11/r12/r14) all produced NaN through an
// unobservable codegen-level mechanism; this compilation is empirically golden.
__global__ __launch_bounds__(256) void k_attn(
    const unsigned short* __restrict__ Q, const unsigned short* __restrict__ K,
    const unsigned short* __restrict__ Vt, unsigned short* __restrict__ Out) {
    int lane = threadIdx.x & 63, wid = threadIdx.x >> 6;
    int c = lane & 15, g = lane >> 4;
    int bid = blockIdx.x;
    int xcd = bid & 7;
    int hgrp = (bid >> 3) & 7;
    int jp = bid >> 6;             // 0..7: pair index
    int bh = hgrp * 8 + xcd;       // 8 heads per XCD cluster -> K/V fits one L2
    const unsigned short* Qh = Q + (size_t)bh * LL * 64;
    const unsigned short* Kh = K + (size_t)bh * LL * 64;
    const unsigned short* Vh = Vt + (size_t)bh * 64 * LL;
    int b = bh >> 4, h = bh & 15;

#ifndef HAVE_MFMA16
    int srcA = 32 * (g & 1) + c;
    int srcB = srcA + 16;
#endif

#pragma unroll 1
    for (int ph = 0; ph < 2; ++ph) {
        int strip = ph ? (15 - jp) : jp;
        int qb = strip * 128 + wid * 32;

        bf16x8 qf[2][2];
#pragma unroll
        for (int qt = 0; qt < 2; qt++)
#pragma unroll
            for (int ch = 0; ch < 2; ch++)
                qf[qt][ch] =
                    *(const bf16x8*)&Qh[(size_t)(qb + qt * 16 + c) * 64 + ch * 32 + g * 8];

        f32x4 acc[2][4];  // [qt][dtile] of out^T: col=q=c, row=d=4g+r
#pragma unroll
        for (int qt = 0; qt < 2; qt++)
#pragma unroll
            for (int dt = 0; dt < 4; dt++) acc[qt][dt] = (f32x4){0.f, 0.f, 0.f, 0.f};
        float m_[2] = {-1e30f, -1e30f}, l_[2] = {0.f, 0.f};

#pragma unroll 1
        for (int kt = 0; kt < qb + 32; kt += 64) {
            bf16x8 kf[4][2];
#pragma unroll
            for (int kt2 = 0; kt2 < 4; kt2++)
#pragma unroll
                for (int ch = 0; ch < 2; ch++)
                    kf[kt2][ch] =
                        *(const bf16x8*)&Kh[(size_t)(kt + kt2 * 16 + c) * 64 + ch * 32 + g * 8];
#ifdef HAVE_MFMA16
            bf16x4 vf[4][4];  // [dt][kt2]: row=d=dt*16+c, kk(k)=4g+e
#pragma unroll
            for (int dt = 0; dt < 4; dt++)
#pragma unroll
                for (int kt2 = 0; kt2 < 4; kt2++)
                    vf[dt][kt2] =
                        *(const bf16x4*)&Vh[(size_t)(dt * 16 + c) * LL + kt + kt2 * 16 + 4 * g];
#else
            bf16x8 vf8[4][2];
#pragma unroll
            for (int dt = 0; dt < 4; dt++)
#pragma unroll
                for (int hf = 0; hf < 2; hf++)
                    vf8[dt][hf] =
                        *(const bf16x8*)&Vh[(size_t)(dt * 16 + c) * LL + kt + hf * 32 + 8 * g];
#endif
#pragma unroll
            for (int qt = 0; qt < 2; qt++) {
                int qtb = qb + qt * 16;
                if (kt > qtb + 15) continue;  // this tile finished (wave-uniform)
                int qrow = qtb + c;
                f32x4 sv[4];
#pragma unroll
                for (int kt2 = 0; kt2 < 4; kt2++) {
                    sv[kt2] = (f32x4){0.f, 0.f, 0.f, 0.f};
                    sv[kt2] = __builtin_amdgcn_mfma_f32_16x16x32_bf16(kf[kt2][0], qf[qt][0],
                                                                      sv[kt2], 0, 0, 0);
                    sv[kt2] = __builtin_amdgcn_mfma_f32_16x16x32_bf16(kf[kt2][1], qf[qt][1],
                                                                      sv[kt2], 0, 0, 0);
                }
                if (kt + 63 > qtb) {
#pragma unroll
                    for (int kt2 = 0; kt2 < 4; kt2++) {
                        if (kt + kt2 * 16 + 15 > qtb) {
#pragma unroll
                            for (int r = 0; r < 4; r++)
                                if (kt + kt2 * 16 + 4 * g + r > qrow) sv[kt2][r] = -1e9f;
                        }
                    }
                }
                float tm = fmaxf(fmaxf(fmaxf(sv[0][0], sv[0][1]), fmaxf(sv[0][2], sv[0][3])),
                                 fmaxf(fmaxf(sv[1][0], sv[1][1]), fmaxf(sv[1][2], sv[1][3])));
                float tm2 = fmaxf(fmaxf(fmaxf(sv[2][0], sv[2][1]), fmaxf(sv[2][2], sv[2][3])),
                                  fmaxf(fmaxf(sv[3][0], sv[3][1]), fmaxf(sv[3][2], sv[3][3])));
                tm = fmaxf(tm, tm2);
                tm = fmaxf(tm, __shfl_xor(tm, 16));
                tm = fmaxf(tm, __shfl_xor(tm, 32));
                // defer-max: logits bounded (|s*log2e| <= ~5.8) -> rescale fires ~once
                if (__any(tm > m_[qt] + 12.0f)) {
                    float mn = fmaxf(m_[qt], tm);
                    float scl = exp2v(m_[qt] - mn);
                    m_[qt] = mn;
                    l_[qt] *= scl;
#pragma unroll
                    for (int dt = 0; dt < 4; dt++) {
                        acc[qt][dt][0] *= scl; acc[qt][dt][1] *= scl;
                        acc[qt][dt][2] *= scl; acc[qt][dt][3] *= scl;
                    }
                }
                float p[4][4];
                float rs = 0.f;
#pragma unroll
                for (int kt2 = 0; kt2 < 4; kt2++)
#pragma unroll
                    for (int r = 0; r < 4; r++) {
                        p[kt2][r] = exp2v(sv[kt2][r] - m_[qt]);
                        rs += p[kt2][r];
                    }
                rs += __shfl_xor(rs, 16);
                rs += __shfl_xor(rs, 32);
                l_[qt] += rs;
#ifdef HAVE_MFMA16
                bf16x4 pbv[4];
#pragma unroll
                for (int kt2 = 0; kt2 < 4; kt2++) {
                    union { unsigned int w[2]; bf16x4 v; } pu;
                    pu.w[0] = cvtpk_bf16(p[kt2][0], p[kt2][1]);
                    pu.w[1] = cvtpk_bf16(p[kt2][2], p[kt2][3]);
                    pbv[kt2] = pu.v;
                }
#pragma unroll
                for (int dt = 0; dt < 4; dt++)
#pragma unroll
                    for (int kt2 = 0; kt2 < 4; kt2++)
                        acc[qt][dt] = __builtin_amdgcn_mfma_f32_16x16x16bf16_1k(
                            vf[dt][kt2], pbv[kt2], acc[qt][dt], 0, 0, 0);
#else
#pragma unroll
                for (int hf = 0; hf < 2; hf++) {
                    unsigned int A0 = cvtpk_bf16(p[2 * hf][0], p[2 * hf][1]);
                    unsigned int A1 = cvtpk_bf16(p[2 * hf][2], p[2 * hf][3]);
                    unsigned int B0 = cvtpk_bf16(p[2 * hf + 1][0], p[2 * hf + 1][1]);
                    unsigned int B1 = cvtpk_bf16(p[2 * hf + 1][2], p[2 * hf + 1][3]);
                    int t0a = __shfl((int)A0, srcA), t0b = __shfl((int)B0, srcA);
                    int t1a = __shfl((int)A1, srcA), t1b = __shfl((int)B1, srcA);
                    int t2a = __shfl((int)A0, srcB), t2b = __shfl((int)B0, srcB);
                    int t3a = __shfl((int)A1, srcB), t3b = __shfl((int)B1, srcB);
                    union { int w[4]; bf16x8 v; } u;
                    bool hi = (g & 2) != 0;
                    u.w[0] = hi ? t0b : t0a;
                    u.w[1] = hi ? t1b : t1a;
                    u.w[2] = hi ? t2b : t2a;
                    u.w[3] = hi ? t3b : t3a;
#pragma unroll
                    for (int dt = 0; dt < 4; dt++)
                        acc[qt][dt] = __builtin_amdgcn_mfma_f32_16x16x32_bf16(
                            vf8[dt][hf], u.v, acc[qt][dt], 0, 0, 0);
                }
#endif
            }
        }
        // epilogue: Out (B,L,C) bf16; lane writes d = dt*16 + 4g + r, q = qb+qt*16+c
#pragma unroll
        for (int qt = 0; qt < 2; qt++) {
            float inv = 1.f / l_[qt];
            int qg = qb + qt * 16 + c;
            size_t ob = ((size_t)b * LL + qg) * CC + h * 64;
#pragma unroll
            for (int dt = 0; dt < 4; dt++) {
                union { unsigned int w[2]; ushort4 v; } o;
                o.w[0] = cvtpk_bf16(acc[qt][dt][0] * inv, acc[qt][dt][1] * inv);
                o.w[1] = cvtpk_bf16(acc[qt][dt][2] * inv, acc[qt][dt][3] * inv);
                *(ushort4*)&Out[ob + dt * 16 + 4 * g] = o.v;
            }
        }
    }
}

extern "C" void kernel_launch(void* const* d_in, const int* in_sizes, int n_in,
                              void* d_out, int out_size, void* d_ws, size_t ws_size,
                              hipStream_t stream) {
    const float* x = (const float*)d_in[0];
    const float* rope = (const float*)d_in[2];
    const float* w1 = (const float*)d_in[3];
    const float* qb = (const float*)d_in[4];
    const float* vb = (const float*)d_in[5];
    const float* w2 = (const float*)d_in[6];
    const float* pb = (const float*)d_in[7];
    const float* smul = (const float*)d_in[8];
    float* out = (float*)d_out;

    char* ws = (char*)d_ws;
    unsigned short* xb = (unsigned short*)(ws + 0);                 // 16777216 B
    unsigned short* w1b = (unsigned short*)(ws + 16777216);         // 6291456
    unsigned short* w2b = (unsigned short*)(ws + 23068672);         // 2097152
    float* biascat = (float*)(ws + 25165824);                       // 12288
    unsigned short* qkvb = (unsigned short*)(ws + 25178112);        // 50331648
    unsigned short* Qb = (unsigned short*)(ws + 75509760);          // 16777216
    unsigned short* Kb = (unsigned short*)(ws + 92286976);          // 16777216
    unsigned short* Vtb = (unsigned short*)(ws + 109064192);        // 16777216
    unsigned short* attb = (unsigned short*)(ws + 125841408);       // 16777216
    if (ws_size < 142618624) return;

    // fused prep: x + w1 + w2 conversions + biascat, one launch
    int ntot = (BB * LL * CC + 3 * CC * CC + CC * CC) / 4;  // 3145728 float4s
    k_prep<<<(ntot + 255) / 256, 256, 0, stream>>>(
        (const float4*)x, (const float4*)w1, (const float4*)w2, qb, vb,
        (ushort4*)xb, (ushort4*)w1b, (ushort4*)w2b, (float4*)biascat);

    k_gemm_bt<unsigned short><<<(8192 / 128) * (3072 / 128), 256, 0, stream>>>(
        xb, w1b, biascat, qkvb, BB * LL, 3 * CC, CC);

    k_qknorm<<<BB * LL * HH / 4, 256, 0, stream>>>(qkvb, rope, smul, Qb, Kb);
    k_vtrans<<<BB * HH * (LL / 64), 256, 0, stream>>>(qkvb, Vtb);
    k_attn<<<512, 256, 0, stream>>>(Qb, Kb, Vtb, attb);

    k_gemm_bt<float><<<(8192 / 128) * (1024 / 128), 256, 0, stream>>>(
        attb, w2b, pb, out, BB * LL, CC, CC);
}

// Round 17
// 320.132 us; speedup vs baseline: 1.5447x; 1.0063x over previous
//
#include <hip/hip_runtime.h>
#include <hip/hip_bf16.h>

#define BB 4
#define LL 2048
#define CC 1024
#define HH 16
#define DD 64
#define HALFD 32

typedef short bf16x8 __attribute__((ext_vector_type(8)));
typedef short bf16x4 __attribute__((ext_vector_type(4)));
typedef float f32x4 __attribute__((ext_vector_type(4)));

#if defined(__has_builtin)
#if __has_builtin(__builtin_amdgcn_mfma_f32_16x16x16bf16_1k)
#define HAVE_MFMA16 1
#endif
#endif

__device__ __forceinline__ float bf2f(unsigned short u) {
    union { unsigned int i; float f; } x; x.i = ((unsigned int)u) << 16; return x.f;
}
__device__ __forceinline__ unsigned short f2bf(float f) {
    union { float f; unsigned int i; } x; x.f = f;
    return (unsigned short)((x.i + 0x7fffu + ((x.i >> 16) & 1u)) >> 16);
}
__device__ __forceinline__ unsigned int cvtpk_bf16(float lo, float hi) {
    unsigned int r;
    asm("v_cvt_pk_bf16_f32 %0, %1, %2" : "=v"(r) : "v"(lo), "v"(hi));
    return r;
}
__device__ __forceinline__ float exp2v(float x) {
    float r;
    asm("v_exp_f32 %0, %1" : "=v"(r) : "v"(x));
    return r;
}
__device__ __forceinline__ void gload_lds16(const void* g, void* l) {
    __builtin_amdgcn_global_load_lds(
        (const __attribute__((address_space(1))) unsigned int*)g,
        (__attribute__((address_space(3))) unsigned int*)l, 16, 0, 0);
}

// ---------------- fused prep: all fp32->bf16 conversions + biascat in ONE launch ----------------
__global__ void k_prep(const float4* __restrict__ x, const float4* __restrict__ w1,
                       const float4* __restrict__ w2, const float* __restrict__ qb,
                       const float* __restrict__ vb, ushort4* __restrict__ xb,
                       ushort4* __restrict__ w1b, ushort4* __restrict__ w2b,
                       float4* __restrict__ biascat) {
    const int N1 = BB * LL * CC / 4;        // 2097152
    const int N2 = 3 * CC * CC / 4;         // 786432
    const int N3 = CC * CC / 4;             // 262144
    int i = blockIdx.x * blockDim.x + threadIdx.x;
    if (i < 768) {  // biascat: 3072 floats = 768 float4
        int e = i * 4;
        float4 o;
        o.x = (e + 0 < CC) ? qb[e + 0] : (e + 0 < 2 * CC ? 0.f : vb[e + 0 - 2 * CC]);
        o.y = (e + 1 < CC) ? qb[e + 1] : (e + 1 < 2 * CC ? 0.f : vb[e + 1 - 2 * CC]);
        o.z = (e + 2 < CC) ? qb[e + 2] : (e + 2 < 2 * CC ? 0.f : vb[e + 2 - 2 * CC]);
        o.w = (e + 3 < CC) ? qb[e + 3] : (e + 3 < 2 * CC ? 0.f : vb[e + 3 - 2 * CC]);
        biascat[i] = o;
    }
    float4 v;
    ushort4* dst;
    if (i < N1) {
        v = x[i];
        dst = &xb[i];
    } else if (i < N1 + N2) {
        v = w1[i - N1];
        dst = &w1b[i - N1];
    } else if (i < N1 + N2 + N3) {
        v = w2[i - N1 - N2];
        dst = &w2b[i - N1 - N2];
    } else {
        return;
    }
    ushort4 o;
    o.x = f2bf(v.x); o.y = f2bf(v.y); o.z = f2bf(v.z); o.w = f2bf(v.w);
    *dst = o;
}

// ---------------- GEMM: C[M,N] = A[M,K] * Bt[N,K]^T + bias[N] ----------------
// 128x128 tile, 4 waves, global_load_lds(16B) staging (m97 pattern).
// K-step 64 via TWO independent [128][32] LDS buffer sets; XCD-bijective tile swizzle.
template <typename OutT>
__global__ __launch_bounds__(256) void k_gemm_bt(
    const unsigned short* __restrict__ A, const unsigned short* __restrict__ Bt,
    const float* __restrict__ bias, OutT* __restrict__ Cout, int M, int N, int K) {
    __shared__ unsigned short As0[128][32];
    __shared__ unsigned short As1[128][32];
    __shared__ unsigned short Bs0[128][32];
    __shared__ unsigned short Bs1[128][32];
    int nwg = gridDim.x;
    int cpx = nwg >> 3;
    int swz = (blockIdx.x & 7) * cpx + (blockIdx.x >> 3);
    int nT = N >> 7;
    int tM = (swz / nT) << 7;
    int tN = (swz % nT) << 7;
    int t = threadIdx.x;
    int lane = t & 63, wid = t >> 6;
    int wr = (wid >> 1) * 64, wc = (wid & 1) * 64;
    int c = lane & 15, g = lane >> 4;

    const unsigned short* gA = A + (size_t)(tM + wid * 32 + (lane >> 2)) * K + (lane & 3) * 8;
    const unsigned short* gB = Bt + (size_t)(tN + wid * 32 + (lane >> 2)) * K + (lane & 3) * 8;
    unsigned short* a00 = &As0[wid * 32][0];
    unsigned short* a01 = &As0[wid * 32 + 16][0];
    unsigned short* a10 = &As1[wid * 32][0];
    unsigned short* a11 = &As1[wid * 32 + 16][0];
    unsigned short* b00 = &Bs0[wid * 32][0];
    unsigned short* b01 = &Bs0[wid * 32 + 16][0];
    unsigned short* b10 = &Bs1[wid * 32][0];
    unsigned short* b11 = &Bs1[wid * 32 + 16][0];
    size_t r16 = (size_t)16 * K;

    f32x4 acc[4][4];
#pragma unroll
    for (int i = 0; i < 4; i++)
#pragma unroll
        for (int j = 0; j < 4; j++) acc[i][j] = (f32x4){0.f, 0.f, 0.f, 0.f};

    for (int k0 = 0; k0 < K; k0 += 64) {
        __syncthreads();
        gload_lds16(gA + k0, a00);
        gload_lds16(gA + k0 + r16, a01);
        gload_lds16(gB + k0, b00);
        gload_lds16(gB + k0 + r16, b01);
        gload_lds16(gA + k0 + 32, a10);
        gload_lds16(gA + k0 + 32 + r16, a11);
        gload_lds16(gB + k0 + 32, b10);
        gload_lds16(gB + k0 + 32 + r16, b11);
        __syncthreads();
        bf16x8 af[4], bfr[4];
#pragma unroll
        for (int fm = 0; fm < 4; fm++) af[fm] = *(const bf16x8*)&As0[wr + fm * 16 + c][g * 8];
#pragma unroll
        for (int fn = 0; fn < 4; fn++) bfr[fn] = *(const bf16x8*)&Bs0[wc + fn * 16 + c][g * 8];
#pragma unroll
        for (int fm = 0; fm < 4; fm++)
#pragma unroll
            for (int fn = 0; fn < 4; fn++)
                acc[fm][fn] = __builtin_amdgcn_mfma_f32_16x16x32_bf16(af[fm], bfr[fn],
                                                                      acc[fm][fn], 0, 0, 0);
#pragma unroll
        for (int fm = 0; fm < 4; fm++) af[fm] = *(const bf16x8*)&As1[wr + fm * 16 + c][g * 8];
#pragma unroll
        for (int fn = 0; fn < 4; fn++) bfr[fn] = *(const bf16x8*)&Bs1[wc + fn * 16 + c][g * 8];
#pragma unroll
        for (int fm = 0; fm < 4; fm++)
#pragma unroll
            for (int fn = 0; fn < 4; fn++)
                acc[fm][fn] = __builtin_amdgcn_mfma_f32_16x16x32_bf16(af[fm], bfr[fn],
                                                                      acc[fm][fn], 0, 0, 0);
    }
#pragma unroll
    for (int fm = 0; fm < 4; fm++) {
#pragma unroll
        for (int fn = 0; fn < 4; fn++) {
            int col = tN + wc + fn * 16 + c;
            float bv = bias[col];
#pragma unroll
            for (int r = 0; r < 4; r++) {
                int row = tM + wr + fm * 16 + g * 4 + r;
                float v = acc[fm][fn][r] + bv;
                if constexpr (sizeof(OutT) == 2)
                    Cout[(size_t)row * N + col] = f2bf(v);
                else
                    Cout[(size_t)row * N + col] = v;
            }
        }
    }
}

// ---------------- fused Q/K norm+RoPE AND V transpose, one launch ----------------
// Blocks [0, 32768): k_qknorm body verbatim (l2norm + scale(+log2e) + RoPE -> Q,K).
// Blocks [32768, 34816): k_vtrans body with ushort4-vectorized global load/store.
__global__ __launch_bounds__(256) void k_qkv_prep(
    const unsigned short* __restrict__ qkv, const float* __restrict__ rope,
    const float* __restrict__ smul, unsigned short* __restrict__ Q,
    unsigned short* __restrict__ Ko, unsigned short* __restrict__ Vt) {
    int bidx = blockIdx.x;
    if (bidx < 32768) {
        // ---- qknorm body (verbatim) ----
        int wid = threadIdx.x >> 6, lane = threadIdx.x & 63;
        long rowid = (long)bidx * 4 + wid;  // (b,l,h), h fastest
        int h = rowid & 15;
        long t2 = rowid >> 4;
        int l = t2 & 2047;
        int b = (int)(t2 >> 11);
        size_t base = ((size_t)(b * LL + l) * 3) * CC + h * 64 + lane;
        float q = bf2f(qkv[base]);
        float k = bf2f(qkv[base + CC]);
        float sq = q * q, sk = k * k;
#pragma unroll
        for (int m = 32; m >= 1; m >>= 1) {
            sq += __shfl_xor(sq, m);
            sk += __shfl_xor(sk, m);
        }
        float sm = expf(fminf(smul[h], 4.6051701859880913680f)) * 1.4426950408889634f;
        q = q / fmaxf(sqrtf(sq), 1e-12f) * sm;
        k = k / fmaxf(sqrtf(sk), 1e-12f);
        int j = lane >> 1;
        float cs = rope[((size_t)(b * 2) * LL + l) * HALFD + j];
        float sn = rope[((size_t)(b * 2 + 1) * LL + l) * HALFD + j];
        float qp = __shfl_xor(q, 1), kp = __shfl_xor(k, 1);
        float qn = (lane & 1) ? (qp * sn + q * cs) : (q * cs - qp * sn);
        float kn = (lane & 1) ? (kp * sn + k * cs) : (k * cs - kp * sn);
        size_t ob = ((size_t)(b * HH + h) * LL + l) * 64 + lane;
        Q[ob] = f2bf(qn);
        Ko[ob] = f2bf(kn);
    } else {
        // ---- vtrans body, ushort4-vectorized global access ----
        __shared__ unsigned short tile[64][65];
        int bid = bidx - 32768;
        int lb = bid & 31;  // L/64
        int bh = bid >> 5;
        int h = bh & 15, b = bh >> 4;
        int t = threadIdx.x;
        for (int i = t; i < 1024; i += 256) {
            int row = i >> 4, d4 = (i & 15) << 2;
            ushort4 v = *(const ushort4*)&qkv[((size_t)(b * LL + lb * 64 + row) * 3 + 2) * CC +
                                              h * 64 + d4];
            tile[row][d4 + 0] = v.x;
            tile[row][d4 + 1] = v.y;
            tile[row][d4 + 2] = v.z;
            tile[row][d4 + 3] = v.w;
        }
        __syncthreads();
        for (int i = t; i < 1024; i += 256) {
            int dd = i >> 4, l4 = (i & 15) << 2;
            ushort4 o;
            o.x = tile[l4 + 0][dd];
            o.y = tile[l4 + 1][dd];
            o.z = tile[l4 + 2][dd];
            o.w = tile[l4 + 3][dd];
            *(ushort4*)&Vt[((size_t)bh * 64 + dd) * LL + lb * 64 + l4] = o;
        }
    }
}

// ---------------- causal flash attention: balanced strip-pair blocks, two phases ----------------
// FROZEN: byte-identical to the round-13 PASSING kernel. Six rounds of body edits
// (r6/r8/r10/r11/r12/r14) all produced NaN via an unobservable codegen-level
// mechanism; this compilation is empirically golden.
__global__ __launch_bounds__(256) void k_attn(
    const unsigned short* __restrict__ Q, const unsigned short* __restrict__ K,
    const unsigned short* __restrict__ Vt, unsigned short* __restrict__ Out) {
    int lane = threadIdx.x & 63, wid = threadIdx.x >> 6;
    int c = lane & 15, g = lane >> 4;
    int bid = blockIdx.x;
    int xcd = bid & 7;
    int hgrp = (bid >> 3) & 7;
    int jp = bid >> 6;             // 0..7: pair index
    int bh = hgrp * 8 + xcd;       // 8 heads per XCD cluster -> K/V fits one L2
    const unsigned short* Qh = Q + (size_t)bh * LL * 64;
    const unsigned short* Kh = K + (size_t)bh * LL * 64;
    const unsigned short* Vh = Vt + (size_t)bh * 64 * LL;
    int b = bh >> 4, h = bh & 15;

#ifndef HAVE_MFMA16
    int srcA = 32 * (g & 1) + c;
    int srcB = srcA + 16;
#endif

#pragma unroll 1
    for (int ph = 0; ph < 2; ++ph) {
        int strip = ph ? (15 - jp) : jp;
        int qb = strip * 128 + wid * 32;

        bf16x8 qf[2][2];
#pragma unroll
        for (int qt = 0; qt < 2; qt++)
#pragma unroll
            for (int ch = 0; ch < 2; ch++)
                qf[qt][ch] =
                    *(const bf16x8*)&Qh[(size_t)(qb + qt * 16 + c) * 64 + ch * 32 + g * 8];

        f32x4 acc[2][4];  // [qt][dtile] of out^T: col=q=c, row=d=4g+r
#pragma unroll
        for (int qt = 0; qt < 2; qt++)
#pragma unroll
            for (int dt = 0; dt < 4; dt++) acc[qt][dt] = (f32x4){0.f, 0.f, 0.f, 0.f};
        float m_[2] = {-1e30f, -1e30f}, l_[2] = {0.f, 0.f};

#pragma unroll 1
        for (int kt = 0; kt < qb + 32; kt += 64) {
            bf16x8 kf[4][2];
#pragma unroll
            for (int kt2 = 0; kt2 < 4; kt2++)
#pragma unroll
                for (int ch = 0; ch < 2; ch++)
                    kf[kt2][ch] =
                        *(const bf16x8*)&Kh[(size_t)(kt + kt2 * 16 + c) * 64 + ch * 32 + g * 8];
#ifdef HAVE_MFMA16
            bf16x4 vf[4][4];  // [dt][kt2]: row=d=dt*16+c, kk(k)=4g+e
#pragma unroll
            for (int dt = 0; dt < 4; dt++)
#pragma unroll
                for (int kt2 = 0; kt2 < 4; kt2++)
                    vf[dt][kt2] =
                        *(const bf16x4*)&Vh[(size_t)(dt * 16 + c) * LL + kt + kt2 * 16 + 4 * g];
#else
            bf16x8 vf8[4][2];
#pragma unroll
            for (int dt = 0; dt < 4; dt++)
#pragma unroll
                for (int hf = 0; hf < 2; hf++)
                    vf8[dt][hf] =
                        *(const bf16x8*)&Vh[(size_t)(dt * 16 + c) * LL + kt + hf * 32 + 8 * g];
#endif
#pragma unroll
            for (int qt = 0; qt < 2; qt++) {
                int qtb = qb + qt * 16;
                if (kt > qtb + 15) continue;  // this tile finished (wave-uniform)
                int qrow = qtb + c;
                f32x4 sv[4];
#pragma unroll
                for (int kt2 = 0; kt2 < 4; kt2++) {
                    sv[kt2] = (f32x4){0.f, 0.f, 0.f, 0.f};
                    sv[kt2] = __builtin_amdgcn_mfma_f32_16x16x32_bf16(kf[kt2][0], qf[qt][0],
                                                                      sv[kt2], 0, 0, 0);
                    sv[kt2] = __builtin_amdgcn_mfma_f32_16x16x32_bf16(kf[kt2][1], qf[qt][1],
                                                                      sv[kt2], 0, 0, 0);
                }
                if (kt + 63 > qtb) {
#pragma unroll
                    for (int kt2 = 0; kt2 < 4; kt2++) {
                        if (kt + kt2 * 16 + 15 > qtb) {
#pragma unroll
                            for (int r = 0; r < 4; r++)
                                if (kt + kt2 * 16 + 4 * g + r > qrow) sv[kt2][r] = -1e9f;
                        }
                    }
                }
                float tm = fmaxf(fmaxf(fmaxf(sv[0][0], sv[0][1]), fmaxf(sv[0][2], sv[0][3])),
                                 fmaxf(fmaxf(sv[1][0], sv[1][1]), fmaxf(sv[1][2], sv[1][3])));
                float tm2 = fmaxf(fmaxf(fmaxf(sv[2][0], sv[2][1]), fmaxf(sv[2][2], sv[2][3])),
                                  fmaxf(fmaxf(sv[3][0], sv[3][1]), fmaxf(sv[3][2], sv[3][3])));
                tm = fmaxf(tm, tm2);
                tm = fmaxf(tm, __shfl_xor(tm, 16));
                tm = fmaxf(tm, __shfl_xor(tm, 32));
                // defer-max: logits bounded (|s*log2e| <= ~5.8) -> rescale fires ~once
                if (__any(tm > m_[qt] + 12.0f)) {
                    float mn = fmaxf(m_[qt], tm);
                    float scl = exp2v(m_[qt] - mn);
                    m_[qt] = mn;
                    l_[qt] *= scl;
#pragma unroll
                    for (int dt = 0; dt < 4; dt++) {
                        acc[qt][dt][0] *= scl; acc[qt][dt][1] *= scl;
                        acc[qt][dt][2] *= scl; acc[qt][dt][3] *= scl;
                    }
                }
                float p[4][4];
                float rs = 0.f;
#pragma unroll
                for (int kt2 = 0; kt2 < 4; kt2++)
#pragma unroll
                    for (int r = 0; r < 4; r++) {
                        p[kt2][r] = exp2v(sv[kt2][r] - m_[qt]);
                        rs += p[kt2][r];
                    }
                rs += __shfl_xor(rs, 16);
                rs += __shfl_xor(rs, 32);
                l_[qt] += rs;
#ifdef HAVE_MFMA16
                bf16x4 pbv[4];
#pragma unroll
                for (int kt2 = 0; kt2 < 4; kt2++) {
                    union { unsigned int w[2]; bf16x4 v; } pu;
                    pu.w[0] = cvtpk_bf16(p[kt2][0], p[kt2][1]);
                    pu.w[1] = cvtpk_bf16(p[kt2][2], p[kt2][3]);
                    pbv[kt2] = pu.v;
                }
#pragma unroll
                for (int dt = 0; dt < 4; dt++)
#pragma unroll
                    for (int kt2 = 0; kt2 < 4; kt2++)
                        acc[qt][dt] = __builtin_amdgcn_mfma_f32_16x16x16bf16_1k(
                            vf[dt][kt2], pbv[kt2], acc[qt][dt], 0, 0, 0);
#else
#pragma unroll
                for (int hf = 0; hf < 2; hf++) {
                    unsigned int A0 = cvtpk_bf16(p[2 * hf][0], p[2 * hf][1]);
                    unsigned int A1 = cvtpk_bf16(p[2 * hf][2], p[2 * hf][3]);
                    unsigned int B0 = cvtpk_bf16(p[2 * hf + 1][0], p[2 * hf + 1][1]);
                    unsigned int B1 = cvtpk_bf16(p[2 * hf + 1][2], p[2 * hf + 1][3]);
                    int t0a = __shfl((int)A0, srcA), t0b = __shfl((int)B0, srcA);
                    int t1a = __shfl((int)A1, srcA), t1b = __shfl((int)B1, srcA);
                    int t2a = __shfl((int)A0, srcB), t2b = __shfl((int)B0, srcB);
                    int t3a = __shfl((int)A1, srcB), t3b = __shfl((int)B1, srcB);
                    union { int w[4]; bf16x8 v; } u;
                    bool hi = (g & 2) != 0;
                    u.w[0] = hi ? t0b : t0a;
                    u.w[1] = hi ? t1b : t1a;
                    u.w[2] = hi ? t2b : t2a;
                    u.w[3] = hi ? t3b : t3a;
#pragma unroll
                    for (int dt = 0; dt < 4; dt++)
                        acc[qt][dt] = __builtin_amdgcn_mfma_f32_16x16x32_bf16(
                            vf8[dt][hf], u.v, acc[qt][dt], 0, 0, 0);
                }
#endif
            }
        }
        // epilogue: Out (B,L,C) bf16; lane writes d = dt*16 + 4g + r, q = qb+qt*16+c
#pragma unroll
        for (int qt = 0; qt < 2; qt++) {
            float inv = 1.f / l_[qt];
            int qg = qb + qt * 16 + c;
            size_t ob = ((size_t)b * LL + qg) * CC + h * 64;
#pragma unroll
            for (int dt = 0; dt < 4; dt++) {
                union { unsigned int w[2]; ushort4 v; } o;
                o.w[0] = cvtpk_bf16(acc[qt][dt][0] * inv, acc[qt][dt][1] * inv);
                o.w[1] = cvtpk_bf16(acc[qt][dt][2] * inv, acc[qt][dt][3] * inv);
                *(ushort4*)&Out[ob + dt * 16 + 4 * g] = o.v;
            }
        }
    }
}

extern "C" void kernel_launch(void* const* d_in, const int* in_sizes, int n_in,
                              void* d_out, int out_size, void* d_ws, size_t ws_size,
                              hipStream_t stream) {
    const float* x = (const float*)d_in[0];
    const float* rope = (const float*)d_in[2];
    const float* w1 = (const float*)d_in[3];
    const float* qb = (const float*)d_in[4];
    const float* vb = (const float*)d_in[5];
    const float* w2 = (const float*)d_in[6];
    const float* pb = (const float*)d_in[7];
    const float* smul = (const float*)d_in[8];
    float* out = (float*)d_out;

    char* ws = (char*)d_ws;
    unsigned short* xb = (unsigned short*)(ws + 0);                 // 16777216 B
    unsigned short* w1b = (unsigned short*)(ws + 16777216);         // 6291456
    unsigned short* w2b = (unsigned short*)(ws + 23068672);         // 2097152
    float* biascat = (float*)(ws + 25165824);                       // 12288
    unsigned short* qkvb = (unsigned short*)(ws + 25178112);        // 50331648
    unsigned short* Qb = (unsigned short*)(ws + 75509760);          // 16777216
    unsigned short* Kb = (unsigned short*)(ws + 92286976);          // 16777216
    unsigned short* Vtb = (unsigned short*)(ws + 109064192);        // 16777216
    unsigned short* attb = (unsigned short*)(ws + 125841408);       // 16777216
    if (ws_size < 142618624) return;

    // fused prep: x + w1 + w2 conversions + biascat, one launch
    int ntot = (BB * LL * CC + 3 * CC * CC + CC * CC) / 4;  // 3145728 float4s
    k_prep<<<(ntot + 255) / 256, 256, 0, stream>>>(
        (const float4*)x, (const float4*)w1, (const float4*)w2, qb, vb,
        (ushort4*)xb, (ushort4*)w1b, (ushort4*)w2b, (float4*)biascat);

    k_gemm_bt<unsigned short><<<(8192 / 128) * (3072 / 128), 256, 0, stream>>>(
        xb, w1b, biascat, qkvb, BB * LL, 3 * CC, CC);

    // fused qknorm (32768 blocks) + vtrans (2048 blocks), one launch
    k_qkv_prep<<<32768 + 2048, 256, 0, stream>>>(qkvb, rope, smul, Qb, Kb, Vtb);

    k_attn<<<512, 256, 0, stream>>>(Qb, Kb, Vtb, attb);

    k_gemm_bt<float><<<(8192 / 128) * (1024 / 128), 256, 0, stream>>>(
        attb, w2b, pb, out, BB * LL, CC, CC);
}